// Round 6
// baseline (1012.020 us; speedup 1.0000x reference)
//
#include <hip/hip_runtime.h>
#include <hip/hip_bf16.h>
#include <math.h>

typedef __hip_bfloat16 bf16;
typedef __attribute__((ext_vector_type(8))) short frag8;
typedef __attribute__((ext_vector_type(4))) float f32x4;
typedef long long ll;

__device__ __forceinline__ float b2f(bf16 v) { return __bfloat162float(v); }
__device__ __forceinline__ bf16 f2b(float v) { return __float2bfloat16(v); }

// pack two floats into one dword of bf16x2
__device__ __forceinline__ unsigned pk2f(float a, float b) {
    union { bf16 h[2]; unsigned u; } c;
    c.h[0] = f2b(a); c.h[1] = f2b(b);
    return c.u;
}
// unpack 8 consecutive bf16 (16B-aligned) into floats
__device__ __forceinline__ void up8(const bf16* p, float* f) {
    const uint4 u = *(const uint4*)p;
    union { unsigned u; bf16 h[2]; } c;
    c.u = u.x; f[0] = b2f(c.h[0]); f[1] = b2f(c.h[1]);
    c.u = u.y; f[2] = b2f(c.h[0]); f[3] = b2f(c.h[1]);
    c.u = u.z; f[4] = b2f(c.h[0]); f[5] = b2f(c.h[1]);
    c.u = u.w; f[6] = b2f(c.h[0]); f[7] = b2f(c.h[1]);
}
// unpack a uint4 of 8 bf16 already in registers
__device__ __forceinline__ void up8u(const uint4 u, float* f) {
    union { unsigned u; bf16 h[2]; } c;
    c.u = u.x; f[0] = b2f(c.h[0]); f[1] = b2f(c.h[1]);
    c.u = u.y; f[2] = b2f(c.h[0]); f[3] = b2f(c.h[1]);
    c.u = u.z; f[4] = b2f(c.h[0]); f[5] = b2f(c.h[1]);
    c.u = u.w; f[6] = b2f(c.h[0]); f[7] = b2f(c.h[1]);
}

#define LN_EPS 1e-5f
#define D_EPS 1e-8f
#define INV_SQRT_M 0.17677669529663687f

// ---------------- dtype sniffer: mode=1 if d_in[0] is float32, 0 if bf16 -------------
__global__ __launch_bounds__(256) void k_sniff(const void* x, int* mode)
{
    __shared__ int cnt;
    if (threadIdx.x == 0) cnt = 0;
    __syncthreads();
    const unsigned short* u = (const unsigned short*)x;
    const unsigned short h = u[2 * threadIdx.x];
    const unsigned int bits = ((unsigned int)h) << 16;
    const float v = __uint_as_float(bits);
    const float a = fabsf(v);
    const bool sane = (h == 0) || (a >= 1e-8f && a <= 1e4f);
    if (!sane) atomicAdd(&cnt, 1);
    __syncthreads();
    if (threadIdx.x == 0) *mode = (cnt > 64) ? 1 : 0;
}

// ---------------- single table-driven convert of all params + x ----------------
struct CvTab { const void* src[28]; int dstOff[28]; int cum[29]; };

__global__ __launch_bounds__(256) void k_convert_all(CvTab tab, bf16* base,
                                                     const int* mode)
{
    const int idx = blockIdx.x * 256 + threadIdx.x;
    if (idx >= tab.cum[28]) return;
    int s = 0;
    while (idx >= tab.cum[s + 1]) ++s;
    const int local = idx - tab.cum[s];
    const float v = (*mode) ? ((const float*)tab.src[s])[local]
                            : b2f(((const bf16*)tab.src[s])[local]);
    base[tab.dstOff[s] + local] = f2b(v);
}

// ---- prologue: pad stage-1 kqv weight [192][27] -> hi/lo bf16 [192][32] ----
__global__ __launch_bounds__(256) void k_prep(
    const void* __restrict__ w1raw, const int* __restrict__ mode,
    bf16* __restrict__ w1ph, bf16* __restrict__ w1pl)
{
    const int idx = blockIdx.x * 256 + threadIdx.x;
    if (idx >= 6144) return;
    const int o = idx >> 5, k = idx & 31;
    float v = 0.f;
    if (k < 27)
        v = (*mode) ? ((const float*)w1raw)[o * 27 + k]
                    : b2f(((const bf16*)w1raw)[o * 27 + k]);
    const bf16 h = f2b(v);
    w1ph[idx] = h;
    w1pl[idx] = f2b(v - b2f(h));
}

// ---- MFMA stage-1 front: unfold27 + LN(27) + kqv GEMM + prm_exp(k,q) ----
__global__ __launch_bounds__(256) void k_fused1(
    const bf16* __restrict__ x, const bf16* __restrict__ w1ph,
    const bf16* __restrict__ w1pl, const bf16* __restrict__ kqvb,
    const bf16* __restrict__ n1g, const bf16* __restrict__ n1b,
    const bf16* __restrict__ pw,
    bf16* __restrict__ KP, bf16* __restrict__ QP, bf16* __restrict__ V,
    float* __restrict__ red, const int b)
{
    // LDS layout (49632 B -> 3 blocks/CU); KPs has its OWN region (no alias).
    __shared__ __align__(16) char smem[49632];
    bf16 (*wps)[72] = (bf16(*)[72])(smem);            // 0..4608
    bf16 (*Ah)[40]  = (bf16(*)[40])(smem + 4608);     // ..9728
    bf16 (*Al)[40]  = (bf16(*)[40])(smem + 9728);     // ..14848
    bf16 (*Th)[72]  = (bf16(*)[72])(smem + 14848);    // ..24064  | alias Vs
    bf16 (*Tl)[72]  = (bf16(*)[72])(smem + 24064);    // ..33280
    bf16 (*Wh)[40]  = (bf16(*)[40])(smem + 33280);    // ..38400
    bf16 (*Wl)[40]  = (bf16(*)[40])(smem + 38400);    // ..43520
    bf16 (*KPs)[40] = (bf16(*)[40])(smem + 43520);    // ..48640 (dedicated)
    bf16 (*Vs)[72]  = (bf16(*)[72])(smem + 14848);    // alias Th (2 barriers apart)
    float* kbs = (float*)(smem + 48640);              // 768
    float* gs  = (float*)(smem + 49408);              // 112
    float* bs  = (float*)(smem + 49520);              // 112

    const int tid = threadIdx.x;
    {
        const int i = tid * 8;
        *(uint4*)(&wps[i >> 6][i & 63]) = *(const uint4*)(pw + i);
    }
    if (tid < 192) kbs[tid] = b2f(kqvb[tid]);
    if (tid < 27) { gs[tid] = b2f(n1g[tid]); bs[tid] = b2f(n1b[tid]); }
    if (blockIdx.x == 0)
        for (int i = tid; i < 2080; i += 256) red[i] = 0.f;

    // ---- unfold + two-pass LN: 4 threads per token (7/7/7/6 values each) ----
    const int tok = tid >> 2, part = tid & 3;
    const int t = blockIdx.x * 64 + tok;
    const int h = t / 224, w = t - h * 224;
    const int d0 = part * 7;
    const int nd = (part == 3) ? 6 : 7;
    float vals[7];
    float s = 0.f;
    #pragma unroll
    for (int q = 0; q < 7; ++q) {
        float val = 0.f;
        if (q < nd) {
            const int d = d0 + q;
            const int c = d / 9, rr = d - c * 9;
            const int pi = rr / 3, pj = rr - pi * 3;
            const int hh = h + pi - 1, ww = w + pj - 1;
            if (hh >= 0 && hh < 224 && ww >= 0 && ww < 224)
                val = b2f(x[((ll)(b * 3 + c) * 224 + hh) * 224 + ww]);
        }
        vals[q] = val; s += val;
    }
    s += __shfl_xor(s, 1, 64);  s += __shfl_xor(s, 2, 64);
    const float mean = s * (1.f / 27.f);
    float s2 = 0.f;
    #pragma unroll
    for (int q = 0; q < 7; ++q) {
        if (q < nd) { const float dd = vals[q] - mean; s2 += dd * dd; }
    }
    s2 += __shfl_xor(s2, 1, 64); s2 += __shfl_xor(s2, 2, 64);
    const float rs = rsqrtf(s2 * (1.f / 27.f) + LN_EPS);
    __syncthreads();   // gs/bs/wps/kbs ready
    #pragma unroll
    for (int q = 0; q < 7; ++q) {
        if (q < nd) {
            const int d = d0 + q;
            const float nv = (vals[q] - mean) * rs * gs[d] + bs[d];
            const bf16 nh = f2b(nv);
            Ah[tok][d] = nh;
            Al[tok][d] = f2b(nv - b2f(nh));
        }
    }
    if (part == 3) {
        #pragma unroll
        for (int d = 27; d < 32; ++d) { Ah[tok][d] = f2b(0.f); Al[tok][d] = f2b(0.f); }
    }

    const int wv = tid >> 6, lane = tid & 63;
    const int l15 = lane & 15;
    const int k8 = (lane >> 4) << 3;
    const int rbase = (lane >> 4) << 2;
    const int srow = tid >> 2;
    const int scol = (tid & 3) << 3;
    const int colg = (tid & 3) << 4;

    float xdK[4], xdQ[4];

    #pragma unroll
    for (int g = 0; g < 3; ++g) {          // 0=K, 1=Q, 2=V
        *(uint4*)(&Wh[srow][scol]) = *(const uint4*)(w1ph + (g * 64 + srow) * 32 + scol);
        *(uint4*)(&Wl[srow][scol]) = *(const uint4*)(w1pl + (g * 64 + srow) * 32 + scol);
        __syncthreads();
        const frag8 ah = *(const frag8*)(&Ah[(wv << 4) + l15][k8]);
        const frag8 al = *(const frag8*)(&Al[(wv << 4) + l15][k8]);
        f32x4 acc[4] = {};
        #pragma unroll
        for (int nt = 0; nt < 4; ++nt) {
            const frag8 bh = *(const frag8*)(&Wh[(nt << 4) + l15][k8]);
            const frag8 bl = *(const frag8*)(&Wl[(nt << 4) + l15][k8]);
            acc[nt] = __builtin_amdgcn_mfma_f32_16x16x32_bf16(ah, bh, acc[nt], 0, 0, 0);
            acc[nt] = __builtin_amdgcn_mfma_f32_16x16x32_bf16(al, bh, acc[nt], 0, 0, 0);
            acc[nt] = __builtin_amdgcn_mfma_f32_16x16x32_bf16(ah, bl, acc[nt], 0, 0, 0);
            acc[nt] = __builtin_amdgcn_mfma_f32_16x16x32_bf16(al, bl, acc[nt], 0, 0, 0);
        }
        float xdp[4] = {0.f, 0.f, 0.f, 0.f};
        #pragma unroll
        for (int nt = 0; nt < 4; ++nt) {
            const int col = (nt << 4) + l15;
            const float bv = kbs[g * 64 + col];
            #pragma unroll
            for (int r = 0; r < 4; ++r) {
                const float tb = acc[nt][r] + bv;
                const int trow = (wv << 4) + rbase + r;
                if (g < 2) {
                    const bf16 th = f2b(tb);
                    Th[trow][col] = th;
                    Tl[trow][col] = f2b(tb - b2f(th));
                    xdp[r] += tb * tb;
                } else {
                    Vs[trow][col] = f2b(tb);
                }
            }
        }
        if (g < 2) {
            #pragma unroll
            for (int r = 0; r < 4; ++r) {
                float v = xdp[r];
                v += __shfl_xor(v, 1, 64); v += __shfl_xor(v, 2, 64);
                v += __shfl_xor(v, 4, 64); v += __shfl_xor(v, 8, 64);
                if (g == 0) xdK[r] = 0.5f * v; else xdQ[r] = 0.5f * v;
            }
        }
        __syncthreads();   // Th/Tl (or Vs) ready; Wh/Wl reads done
        if (g < 2) {
            f32x4 acc2[2] = {};
            #pragma unroll
            for (int k0 = 0; k0 < 64; k0 += 32) {
                const frag8 ath = *(const frag8*)(&Th[(wv << 4) + l15][k8 + k0]);
                const frag8 atl = *(const frag8*)(&Tl[(wv << 4) + l15][k8 + k0]);
                #pragma unroll
                for (int nt = 0; nt < 2; ++nt) {
                    const frag8 bw = *(const frag8*)(&wps[(nt << 4) + l15][k8 + k0]);
                    acc2[nt] = __builtin_amdgcn_mfma_f32_16x16x32_bf16(ath, bw, acc2[nt], 0, 0, 0);
                    acc2[nt] = __builtin_amdgcn_mfma_f32_16x16x32_bf16(atl, bw, acc2[nt], 0, 0, 0);
                }
            }
            #pragma unroll
            for (int nt = 0; nt < 2; ++nt)
                #pragma unroll
                for (int r = 0; r < 4; ++r) {
                    const float xd = (g == 0) ? xdK[r] : xdQ[r];
                    const float p = expf(fminf(acc2[nt][r] - xd, 30.f)) * INV_SQRT_M;
                    KPs[(wv << 4) + rbase + r][(nt << 4) + l15] = f2b(p);
                }
            __syncthreads();   // KPs ready
            bf16* dstP = (g == 0 ? KP : QP) + ((ll)blockIdx.x * 64 + srow) * 32 + scol;
            *(uint4*)dstP = *(const uint4*)(&KPs[srow][scol]);
            __syncthreads();   // KPs reads done before next group reuses it
        } else {
            bf16* dstV = V + ((ll)blockIdx.x * 64 + srow) * 64 + colg;
            *(uint4*)dstV       = *(const uint4*)(&Vs[srow][colg]);
            *(uint4*)(dstV + 8) = *(const uint4*)(&Vs[srow][colg + 8]);
        }
    }
}

// ---- MFMA reduce over tokens: red[n*32+m] += sum_t V[t][n]*KP[t][m]; ksum via ones ----
__global__ __launch_bounds__(256) void k_reduce(
    const bf16* __restrict__ kpB, const bf16* __restrict__ vB, const int vstride,
    const int T, float* __restrict__ redBase, const int chunk)
{
    __shared__ bf16 VT[64][72];   // [n][t]
    __shared__ bf16 KT[32][72];   // [m][t]
    const int bz = blockIdx.y;
    const bf16* kp = kpB + (ll)bz * T * 32;
    const bf16* v  = vB + (ll)bz * T * (ll)vstride;
    float* red = redBase + (ll)bz * 2080;
    const int tid = threadIdx.x;
    const int wv = tid >> 6, lane = tid & 63;
    const int l15 = lane & 15, k8 = (lane >> 4) << 3, rbase = (lane >> 4) << 2;
    const int t0 = blockIdx.x * chunk;

    frag8 ones;
    {
        union { bf16 h; short s; } u; u.h = f2b(1.f);
        #pragma unroll
        for (int i = 0; i < 8; ++i) ones[i] = u.s;
    }

    f32x4 acc[2] = {};
    f32x4 accK[2] = {};

    for (int tt = 0; tt < chunk; tt += 64) {
        const int tb = t0 + tt;
        __syncthreads();
        {
            const int tk = tid >> 2, n0 = (tid & 3) << 4;
            const bf16* src = v + (ll)(tb + tk) * vstride + n0;
            bf16 tmp[16];
            *(uint4*)tmp       = *(const uint4*)src;
            *(uint4*)(tmp + 8) = *(const uint4*)(src + 8);
            #pragma unroll
            for (int j = 0; j < 16; ++j) VT[n0 + j][tk] = tmp[j];
        }
        {
            const int tk = tid >> 2, m0 = (tid & 3) << 3;
            const bf16* src = kp + (ll)(tb + tk) * 32 + m0;
            bf16 tmp[8];
            *(uint4*)tmp = *(const uint4*)src;
            #pragma unroll
            for (int j = 0; j < 8; ++j) KT[m0 + j][tk] = tmp[j];
        }
        __syncthreads();
        #pragma unroll
        for (int ks = 0; ks < 2; ++ks) {
            const frag8 af = *(const frag8*)(&VT[(wv << 4) + l15][k8 + ks * 32]);
            #pragma unroll
            for (int tn = 0; tn < 2; ++tn) {
                const frag8 bfv = *(const frag8*)(&KT[(tn << 4) + l15][k8 + ks * 32]);
                acc[tn] = __builtin_amdgcn_mfma_f32_16x16x32_bf16(af, bfv, acc[tn], 0, 0, 0);
            }
            if (wv == 0) {
                #pragma unroll
                for (int tn = 0; tn < 2; ++tn) {
                    const frag8 bfv = *(const frag8*)(&KT[(tn << 4) + l15][k8 + ks * 32]);
                    accK[tn] = __builtin_amdgcn_mfma_f32_16x16x32_bf16(ones, bfv, accK[tn], 0, 0, 0);
                }
            }
        }
    }
    #pragma unroll
    for (int tn = 0; tn < 2; ++tn) {
        const int m = (tn << 4) + l15;
        #pragma unroll
        for (int r = 0; r < 4; ++r) {
            const int n = (wv << 4) + rbase + r;
            atomicAdd(&red[n * 32 + m], acc[tn][r]);
        }
    }
    if (wv == 0 && (lane >> 4) == 0) {
        #pragma unroll
        for (int tn = 0; tn < 2; ++tn)
            atomicAdd(&red[2048 + (tn << 4) + l15], accK[tn][0]);
    }
}

// ---- merged post-attention + LN + MLP (bit-identical to old k_posta -> k_mlpln) ----
__global__ __launch_bounds__(256) void k_postmlp(
    const bf16* __restrict__ qpB, const float* __restrict__ redBase,
    const bf16* __restrict__ vB, const int vstride,
    const bf16* __restrict__ pw, const bf16* __restrict__ pb,
    const bf16* __restrict__ n2g, const bf16* __restrict__ n2b,
    const bf16* __restrict__ w1, const bf16* __restrict__ b1,
    const bf16* __restrict__ w2, const bf16* __restrict__ b2,
    bf16* outB, const int T)
{
    __shared__ __align__(16) char smem[47232];
    bf16 (*QPs)[40] = (bf16(*)[40])(smem);
    bf16 (*KH)[40]  = (bf16(*)[40])(smem + 5120);
    bf16 (*KL)[40]  = (bf16(*)[40])(smem + 10240);
    float (*Cs)[72] = (float(*)[72])(smem);
    bf16 (*W1s)[72] = (bf16(*)[72])(smem);
    bf16 (*W2s)[72] = (bf16(*)[72])(smem + 9216);
    bf16 (*PWs)[72] = (bf16(*)[72])(smem + 18432);
    bf16 (*Gs)[72]  = (bf16(*)[72])(smem + 18432);
    bf16 (*Y0H)[72] = (bf16(*)[72])(smem + 27648);
    bf16 (*Ys)[72]  = (bf16(*)[72])(smem + 27648);
    bf16 (*Y0L)[72] = (bf16(*)[72])(smem + 36864);
    bf16 (*Hn)[72]  = (bf16(*)[72])(smem + 36864);
    float* invs  = (float*)(smem + 46080);
    float* pbs   = (float*)(smem + 46336);
    float* ksums = (float*)(smem + 46592);
    float* mns   = (float*)(smem + 46720);
    float* rss   = (float*)(smem + 46976);

    const int tid = threadIdx.x;
    const int bz = blockIdx.y;
    const float* red = redBase + (ll)bz * 2080;
    const bf16* qp = qpB + (ll)bz * (ll)T * 32;
    const bf16* v  = vB + (ll)bz * (ll)T * (ll)vstride;
    bf16* out = outB + (ll)bz * (ll)T * 64;
    const ll m0 = (ll)blockIdx.x * 64;

    const int lr = tid >> 2;
    const int lc8 = (tid & 3) << 3;
    const int lc16 = (tid & 3) << 4;

    *(uint4*)(&QPs[lr][lc8]) = *(const uint4*)(qp + (m0 + lr) * 32 + lc8);
    *(uint4*)(&PWs[lr][lc16])     = *(const uint4*)(pw + lr * 64 + lc16);
    *(uint4*)(&PWs[lr][lc16 + 8]) = *(const uint4*)(pw + lr * 64 + lc16 + 8);
    {
        const int i0 = tid * 8;
        const float4 a = *(const float4*)(red + i0);
        const float4 b = *(const float4*)(red + i0 + 4);
        const int n = i0 >> 5, m = i0 & 31;
        float xs[8] = {a.x, a.y, a.z, a.w, b.x, b.y, b.z, b.w};
        #pragma unroll
        for (int k = 0; k < 8; ++k) {
            const bf16 h = f2b(xs[k]);
            KH[n][m + k] = h;
            KL[n][m + k] = f2b(xs[k] - b2f(h));
        }
    }
    if (tid < 32) ksums[tid] = red[2048 + tid];
    if (tid < 64) pbs[tid] = b2f(pb[tid]);
    __syncthreads();

    if (tid < 64) {
        float D = D_EPS;
        #pragma unroll
        for (int m = 0; m < 32; ++m) D += b2f(QPs[tid][m]) * ksums[m];
        invs[tid] = 1.f / D;
    }

    const int wv = tid >> 6, lane = tid & 63;
    const int l15 = lane & 15;
    const int mr = (wv << 4) + l15;
    const int k8 = (lane >> 4) << 3;
    const int rbase = (lane >> 4) << 2;

    f32x4 acc[4] = {};
    {
        const frag8 af = *(const frag8*)(&QPs[mr][k8]);
        #pragma unroll
        for (int tn = 0; tn < 4; ++tn) {
            const int nr = (tn << 4) + l15;
            const frag8 bh = *(const frag8*)(&KH[nr][k8]);
            acc[tn] = __builtin_amdgcn_mfma_f32_16x16x32_bf16(af, bh, acc[tn], 0, 0, 0);
            const frag8 bl = *(const frag8*)(&KL[nr][k8]);
            acc[tn] = __builtin_amdgcn_mfma_f32_16x16x32_bf16(af, bl, acc[tn], 0, 0, 0);
        }
    }
    #pragma unroll
    for (int tn = 0; tn < 4; ++tn) {
        const int n = (tn << 4) + l15;
        #pragma unroll
        for (int r = 0; r < 4; ++r) {
            const float x = acc[tn][r];
            const bf16 h = f2b(x);
            Y0H[(wv << 4) + rbase + r][n] = h;
            Y0L[(wv << 4) + rbase + r][n] = f2b(x - b2f(h));
        }
    }
    __syncthreads();

    f32x4 acc2[4] = {};
    #pragma unroll
    for (int k0 = 0; k0 < 64; k0 += 32) {
        const frag8 ah = *(const frag8*)(&Y0H[mr][k8 + k0]);
        const frag8 al = *(const frag8*)(&Y0L[mr][k8 + k0]);
        #pragma unroll
        for (int tn = 0; tn < 4; ++tn) {
            const frag8 bw = *(const frag8*)(&PWs[(tn << 4) + l15][k8 + k0]);
            acc2[tn] = __builtin_amdgcn_mfma_f32_16x16x32_bf16(ah, bw, acc2[tn], 0, 0, 0);
            acc2[tn] = __builtin_amdgcn_mfma_f32_16x16x32_bf16(al, bw, acc2[tn], 0, 0, 0);
        }
    }
    #pragma unroll
    for (int tn = 0; tn < 4; ++tn) {
        const int n = (tn << 4) + l15;
        #pragma unroll
        for (int r = 0; r < 4; ++r) {
            const int row = (wv << 4) + rbase + r;
            Cs[row][n] = acc2[tn][r] * invs[row] + pbs[n];
        }
    }
    __syncthreads();

    {
        const int row = tid >> 2;
        const bf16* vsrc = v + (m0 + row) * (ll)vstride + lc16;
        #pragma unroll
        for (int hh = 0; hh < 2; ++hh) {
            float vv[8];
            up8(vsrc + hh * 8, vv);
            const float* cp = &Cs[row][lc16 + hh * 8];
            uint4 st;
            st.x = pk2f(cp[0] + vv[0], cp[1] + vv[1]);
            st.y = pk2f(cp[2] + vv[2], cp[3] + vv[3]);
            st.z = pk2f(cp[4] + vv[4], cp[5] + vv[5]);
            st.w = pk2f(cp[6] + vv[6], cp[7] + vv[7]);
            *(uint4*)(&Ys[row][lc16 + hh * 8]) = st;
        }
    }
    __syncthreads();

    if (tid < 64) {
        float s = 0.f, s2 = 0.f;
        #pragma unroll
        for (int n = 0; n < 64; ++n) { const float vv = b2f(Ys[tid][n]); s += vv; s2 += vv * vv; }
        const float mn = s * (1.f / 64.f);
        const float var = fmaxf(s2 * (1.f / 64.f) - mn * mn, 0.f);
        mns[tid] = mn; rss[tid] = rsqrtf(var + LN_EPS);
    }
    *(uint4*)(&W1s[lr][lc16])     = *(const uint4*)(w1 + lr * 64 + lc16);
    *(uint4*)(&W1s[lr][lc16 + 8]) = *(const uint4*)(w1 + lr * 64 + lc16 + 8);
    *(uint4*)(&W2s[lr][lc16])     = *(const uint4*)(w2 + lr * 64 + lc16);
    *(uint4*)(&W2s[lr][lc16 + 8]) = *(const uint4*)(w2 + lr * 64 + lc16 + 8);
    __syncthreads();

    for (int i = tid; i < 4096; i += 256) {
        const int r = i >> 6, c = i & 63;
        Hn[r][c] = f2b((b2f(Ys[r][c]) - mns[r]) * rss[r] * b2f(n2g[c]) + b2f(n2b[c]));
    }
    __syncthreads();

    f32x4 accm[4] = {};
    #pragma unroll
    for (int k0 = 0; k0 < 64; k0 += 32) {
        const frag8 af = *(const frag8*)(&Hn[mr][k8 + k0]);
        #pragma unroll
        for (int tn = 0; tn < 4; ++tn) {
            const frag8 bfv = *(const frag8*)(&W1s[(tn << 4) + l15][k8 + k0]);
            accm[tn] = __builtin_amdgcn_mfma_f32_16x16x32_bf16(af, bfv, accm[tn], 0, 0, 0);
        }
    }
    #pragma unroll
    for (int tn = 0; tn < 4; ++tn) {
        const int n = (tn << 4) + l15;
        const float bv = b2f(b1[n]);
        #pragma unroll
        for (int r = 0; r < 4; ++r) {
            float vg = accm[tn][r] + bv;
            vg = 0.5f * vg * (1.f + erff(vg * 0.70710678118654752f));
            Gs[(wv << 4) + rbase + r][n] = f2b(vg);
        }
    }
    __syncthreads();

    f32x4 accn[4] = {};
    #pragma unroll
    for (int k0 = 0; k0 < 64; k0 += 32) {
        const frag8 af = *(const frag8*)(&Gs[mr][k8 + k0]);
        #pragma unroll
        for (int tn = 0; tn < 4; ++tn) {
            const frag8 bfv = *(const frag8*)(&W2s[(tn << 4) + l15][k8 + k0]);
            accn[tn] = __builtin_amdgcn_mfma_f32_16x16x32_bf16(af, bfv, accn[tn], 0, 0, 0);
        }
    }
    #pragma unroll
    for (int tn = 0; tn < 4; ++tn) {
        const int n = (tn << 4) + l15;
        const float bv = b2f(b2[n]);
        #pragma unroll
        for (int r = 0; r < 4; ++r)
            Hn[(wv << 4) + rbase + r][n] = f2b(accn[tn][r] + bv);
    }
    __syncthreads();

    {
        const int row = tid >> 2;
        bf16* dst = out + (m0 + row) * 64 + lc16;
        #pragma unroll
        for (int hh = 0; hh < 2; ++hh) {
            float sv[8], rv[8];
            up8(&Hn[row][lc16 + hh * 8], sv);
            up8(&Ys[row][lc16 + hh * 8], rv);
            uint4 st;
            st.x = pk2f(sv[0] + rv[0], sv[1] + rv[1]);
            st.y = pk2f(sv[2] + rv[2], sv[3] + rv[3]);
            st.z = pk2f(sv[4] + rv[4], sv[5] + rv[5]);
            st.w = pk2f(sv[6] + rv[6], sv[7] + rv[7]);
            *(uint4*)(dst + hh * 8) = st;
        }
    }
}

// ---- unfold 3x3 s2 p1, token-major [Hin*Hin,64] -> [Ho*Ho,576] (+opt LN) ----
__global__ __launch_bounds__(256) void k_unfold576(
    const bf16* __restrict__ in, const int Hin, const int Ho,
    const bf16* __restrict__ g, const bf16* __restrict__ bb,
    const int do_ln, bf16* __restrict__ A,
    const ll inBStride, const ll outBStride)
{
    in += (ll)blockIdx.y * inBStride;
    A  += (ll)blockIdx.y * outBStride;
    const int t = blockIdx.x * 4 + (threadIdx.x >> 6);
    const int l = threadIdx.x & 63;
    const int ho = t / Ho, wo = t - ho * Ho;
    float vals[9];
    float s = 0.f;
    #pragma unroll
    for (int r = 0; r < 9; ++r) {
        const int d = l + (r << 6);
        const int c = d / 9;
        const int rr = d - c * 9;
        const int i = rr / 3, j = rr - i * 3;
        const int hh = 2 * ho + i - 1, ww = 2 * wo + j - 1;
        float val = 0.f;
        if (hh >= 0 && hh < Hin && ww >= 0 && ww < Hin)
            val = b2f(in[((ll)hh * Hin + ww) * 64 + c]);
        vals[r] = val; s += val;
    }
    bf16* out = A + (ll)t * 576;
    if (do_ln) {
        #pragma unroll
        for (int o = 32; o > 0; o >>= 1) s += __shfl_xor(s, o, 64);
        const float mean = s * (1.f / 576.f);
        float s2 = 0.f;
        #pragma unroll
        for (int r = 0; r < 9; ++r) { const float dd = vals[r] - mean; s2 += dd * dd; }
        #pragma unroll
        for (int o = 32; o > 0; o >>= 1) s2 += __shfl_xor(s2, o, 64);
        const float rs = rsqrtf(s2 * (1.f / 576.f) + LN_EPS);
        #pragma unroll
        for (int r = 0; r < 9; ++r) {
            const int d = l + (r << 6);
            out[d] = f2b((vals[r] - mean) * rs * b2f(g[d]) + b2f(bb[d]));
        }
    } else {
        #pragma unroll
        for (int r = 0; r < 9; ++r) out[l + (r << 6)] = f2b(vals[r]);
    }
}

// ---- MFMA bf16 GEMM: C[M,N] = A@W^T + bias (+res); double-buffered K-loop ----
// 1-D grid with bijective XCD-chunk swizzle (n fastest inside chunk -> A-window
// per XCD fits its 4MB L2). fp32 output path stages through LDS for coalesced
// uint4 stores.
__global__ __launch_bounds__(256) void k_gemm(
    const bf16* __restrict__ A, const int lda,
    const bf16* __restrict__ W,
    const bf16* __restrict__ bias,
    const bf16* res, const int ldres,
    void* C, const int ldc, const ll mOff,
    const int K, const int* outm, const int gridN)
{
    __shared__ bf16 As[2][64][40];
    __shared__ bf16 Bs[2][64][40];
    __shared__ __align__(16) char epi[17408];     // f32[64][68] | bf16[64][72]
    float (*Cf)[68] = (float(*)[68])epi;
    bf16 (*Cs)[72] = (bf16(*)[72])epi;

    // bijective XCD-chunk swizzle (m204): consecutive blockIdx round-robin the
    // 8 XCDs; give each XCD a contiguous wgid range. wgid = m*gridN + n.
    const int nwg = gridDim.x;
    const int orig = blockIdx.x;
    const int xcd = orig & 7;
    const int q = nwg >> 3, r = nwg & 7;
    const int wgid = (xcd < r ? xcd * (q + 1) : r * (q + 1) + (xcd - r) * q)
                     + (orig >> 3);
    const int mTile = wgid / gridN;
    const int nTile = wgid - mTile * gridN;
    const ll m0 = (ll)mTile * 64;
    const int n0 = nTile * 64;

    const int tid = threadIdx.x;
    const int wv = tid >> 6;
    const int lane = tid & 63;
    f32x4 acc[4] = {};
    const int lr = tid >> 2;
    const int lc = (tid & 3) << 3;
    const int mr = (wv << 4) + (lane & 15);
    const int k8 = (lane >> 4) << 3;
    const bf16* Ag = A + (m0 + lr) * (ll)lda + lc;
    const bf16* Wg = W + (ll)(n0 + lr) * K + lc;

    uint4 av  = *(const uint4*)(Ag);
    uint4 wv4 = *(const uint4*)(Wg);
    *(uint4*)(&As[0][lr][lc]) = av;
    *(uint4*)(&Bs[0][lr][lc]) = wv4;
    int cur = 0;
    __syncthreads();
    for (int k0 = 0; k0 < K; k0 += 32) {
        const bool nxt = (k0 + 32 < K);
        if (nxt) {
            av  = *(const uint4*)(Ag + k0 + 32);
            wv4 = *(const uint4*)(Wg + k0 + 32);
        }
        const frag8 af = *(const frag8*)(&As[cur][mr][k8]);
        #pragma unroll
        for (int tn = 0; tn < 4; ++tn) {
            const frag8 bfv = *(const frag8*)(&Bs[cur][(tn << 4) + (lane & 15)][k8]);
            acc[tn] = __builtin_amdgcn_mfma_f32_16x16x32_bf16(af, bfv, acc[tn], 0, 0, 0);
        }
        if (nxt) {
            *(uint4*)(&As[cur ^ 1][lr][lc]) = av;
            *(uint4*)(&Bs[cur ^ 1][lr][lc]) = wv4;
        }
        __syncthreads();
        cur ^= 1;
    }
    const int om = outm ? *outm : 0;
    const int rbase = (lane >> 4) << 2;
    if (om) {   // fp32 output: stage f32 in LDS, coalesced uint4 stores
        #pragma unroll
        for (int tn = 0; tn < 4; ++tn) {
            const int nl = (tn << 4) + (lane & 15);
            const float bv = bias ? b2f(bias[n0 + nl]) : 0.f;
            #pragma unroll
            for (int r = 0; r < 4; ++r) {
                const ll m = m0 + (wv << 4) + rbase + r;
                float v = acc[tn][r] + bv;
                if (res) v += b2f(res[m * (ll)ldres + n0 + nl]);
                Cf[(wv << 4) + rbase + r][nl] = v;
            }
        }
        __syncthreads();
        const int row = tid >> 2;
        const int cg = (tid & 3) << 4;
        float* dst = (float*)C + (m0 + mOff + row) * (ll)ldc + n0 + cg;
        #pragma unroll
        for (int u = 0; u < 4; ++u)
            *(uint4*)(dst + u * 4) = *(const uint4*)(&Cf[row][cg + u * 4]);
        return;
    }
    #pragma unroll
    for (int tn = 0; tn < 4; ++tn) {
        const int nl = (tn << 4) + (lane & 15);
        const float bv = bias ? b2f(bias[n0 + nl]) : 0.f;
        #pragma unroll
        for (int r = 0; r < 4; ++r) {
            const ll m = m0 + (wv << 4) + rbase + r;
            float v = acc[tn][r] + bv;
            if (res) v += b2f(res[m * (ll)ldres + n0 + nl]);
            Cs[(wv << 4) + rbase + r][nl] = f2b(v);
        }
    }
    __syncthreads();
    const int row = tid >> 2;
    const int colg = (tid & 3) << 4;
    bf16* dst = (bf16*)C + (m0 + mOff + row) * (ll)ldc + n0 + colg;
    *(uint4*)dst       = *(const uint4*)(&Cs[row][colg]);
    *(uint4*)(dst + 8) = *(const uint4*)(&Cs[row][colg + 8]);
}

// ---- MFMA prm_exp for stage-2 (k and q passes) + RED zeroing ----
__global__ __launch_bounds__(256) void k_fusedP2(
    const bf16* __restrict__ kqv, const bf16* __restrict__ pw,
    bf16* __restrict__ KP, bf16* __restrict__ QP,
    float* __restrict__ redBase, const int T)
{
    __shared__ __align__(16) char smem[19200];
    bf16 (*Ks)[72]  = (bf16(*)[72])(smem);            // 9216
    bf16 (*wps)[72] = (bf16(*)[72])(smem + 9216);     // 4608
    bf16 (*KPs)[40] = (bf16(*)[40])(smem + 13824);    // 5120
    float* xds = (float*)(smem + 18944);              // 256

    const int tid = threadIdx.x;
    const int bz = blockIdx.y;
    {
        const int i = tid * 8;
        *(uint4*)(&wps[i >> 6][i & 63]) = *(const uint4*)(pw + i);
    }
    if (blockIdx.x == 0) {
        float* red = redBase + (ll)bz * 2080;
        for (int i = tid; i < 2080; i += 256) red[i] = 0.f;
    }
    const ll gt0 = (ll)bz * T + (ll)blockIdx.x * 64;
    const int srow = tid >> 2;
    const int colg = (tid & 3) << 4;
    const int scol = (tid & 3) << 3;
    const int wv = tid >> 6, lane = tid & 63;
    const int l15 = lane & 15, k8 = (lane >> 4) << 3, rbase = (lane >> 4) << 2;

    #pragma unroll
    for (int p = 0; p < 2; ++p) {          // 0 = k pass, 1 = q pass
        const bf16* src = kqv + (gt0 + srow) * 192 + p * 64 + colg;
        const uint4 u0 = *(const uint4*)src;
        const uint4 u1 = *(const uint4*)(src + 8);
        *(uint4*)(&Ks[srow][colg])     = u0;
        *(uint4*)(&Ks[srow][colg + 8]) = u1;
        float f0[8], f1[8];
        up8u(u0, f0); up8u(u1, f1);
        float s2 = 0.f;
        #pragma unroll
        for (int k = 0; k < 8; ++k) s2 += f0[k] * f0[k] + f1[k] * f1[k];
        s2 += __shfl_xor(s2, 1, 64); s2 += __shfl_xor(s2, 2, 64);
        if ((tid & 3) == 0) xds[srow] = 0.5f * s2;
        __syncthreads();
        f32x4 acc2[2] = {};
        #pragma unroll
        for (int k0 = 0; k0 < 64; k0 += 32) {
            const frag8 af = *(const frag8*)(&Ks[(wv << 4) + l15][k8 + k0]);
            #pragma unroll
            for (int nt = 0; nt < 2; ++nt) {
                const frag8 bw = *(const frag8*)(&wps[(nt << 4) + l15][k8 + k0]);
                acc2[nt] = __builtin_amdgcn_mfma_f32_16x16x32_bf16(af, bw, acc2[nt], 0, 0, 0);
            }
        }
        #pragma unroll
        for (int nt = 0; nt < 2; ++nt)
            #pragma unroll
            for (int r = 0; r < 4; ++r) {
                const int trow = (wv << 4) + rbase + r;
                const float pv = expf(fminf(acc2[nt][r] - xds[trow], 30.f)) * INV_SQRT_M;
                KPs[trow][(nt << 4) + l15] = f2b(pv);
            }
        __syncthreads();
        bf16* dst = (p == 0 ? KP : QP) + (gt0 + srow) * 32 + scol;
        *(uint4*)dst = *(const uint4*)(&KPs[srow][scol]);
        __syncthreads();   // before next pass overwrites Ks/xds/KPs
    }
}

extern "C" void kernel_launch(void* const* d_in, const int* in_sizes, int n_in,
                              void* d_out, int out_size, void* d_ws, size_t ws_size,
                              hipStream_t stream)
{
    (void)in_sizes; (void)n_in; (void)out_size;
    const int T1 = 50176, T2 = 12544;
    char* ws = (char*)d_ws;

    // ---- cursor-based workspace allocation ----
    size_t cur = 0;
    auto alloc = [&](size_t bytes) {
        size_t r = cur; cur += (bytes + 127) & ~(size_t)127; return r;
    };
    static const int segIdx[28] = {0, 2, 3, 4, 5, 6, 7, 8, 9, 10, 11, 12, 13,
                                   14, 15, 16, 17, 18, 19, 20, 21, 22, 23, 24, 25, 26, 27, 28};
    static const int segN[28] = {1204224, 192, 4096, 64, 27, 27, 64, 64, 4096, 64, 4096, 64, 2048,
                                 110592, 192, 4096, 64, 576, 576, 64, 64, 4096, 64, 4096, 64, 2048,
                                 442368, 768};
    size_t segOff[28];
    for (int i = 0; i < 28; ++i) segOff[i] = alloc((size_t)segN[i] * 2);
    const size_t oMODE = alloc(256);
    const size_t oRED  = alloc(66560);             // 8 x 2080 fp32
    const size_t oW1P  = alloc(24576);             // hi/lo padded [192][32] bf16
    const size_t oBIG  = alloc(6422528);           // [T1,64]
    const size_t oKP   = alloc(3211264);           // [T1,32]
    const size_t oQP   = alloc(3211264);           // [T1,32]
    (void)oQP;

    bf16* P[28];
    for (int i = 0; i < 28; ++i) P[i] = (bf16*)(ws + segOff[i]);
    bf16* XC = P[0];
    bf16 *P1KQVB = P[1], *P1PW = P[2], *P1PB = P[3], *P1N1G = P[4], *P1N1B = P[5];
    bf16 *P1N2G = P[6], *P1N2B = P[7], *P1M1W = P[8], *P1M1B = P[9], *P1M2W = P[10];
    bf16 *P1M2B = P[11], *P1W = P[12];
    bf16 *P2KQVW = P[13], *P2KQVB = P[14], *P2PW = P[15], *P2PB = P[16];
    bf16 *P2N1G = P[17], *P2N1B = P[18], *P2N2G = P[19], *P2N2B = P[20];
    bf16 *P2M1W = P[21], *P2M1B = P[22], *P2M2W = P[23], *P2M2B = P[24], *P2W = P[25];
    bf16 *PROJW = P[26], *PROJB = P[27];

    int*   MODE = (int*)(ws + oMODE);
    float* REDF = (float*)(ws + oRED);
    bf16*  W1PH = (bf16*)(ws + oW1P);
    bf16*  W1PL = (bf16*)(ws + oW1P + 12288);
    bf16*  BIG  = (bf16*)(ws + oBIG);              // stage-1 V/Y/OUT (in-place chain)
    bf16*  KP   = (bf16*)(ws + oKP);
    bf16*  QP   = (bf16*)(ws + oKP + 3211264);
    bf16*  A2   = (bf16*)(ws + oKP);               // [T2,576] over dead KP/QP
    bf16*  KQV2F = (bf16*)d_out;                   // [8*T2,192] scratch in d_out
    bf16*  KP2F  = (bf16*)(ws + oKP);              // [8*T2,32]
    bf16*  QP2F  = (bf16*)(ws + oKP + 6422528);    // [8*T2,32]
    bf16*  YB2F  = (bf16*)(ws + oBIG);             // [8*T2,64] (over BIG, dead)
    bf16*  A3c   = (bf16*)(ws + oBIG + 12845056);  // [6272,576] chunk

    // ---- prologue ----
    k_sniff<<<1, 256, 0, stream>>>(d_in[0], MODE);
    CvTab tab;
    int cum = 0;
    for (int i = 0; i < 28; ++i) {
        tab.src[i] = d_in[segIdx[i]];
        tab.dstOff[i] = (int)(segOff[i] / 2);
        tab.cum[i] = cum;
        cum += segN[i];
    }
    tab.cum[28] = cum;
    k_convert_all<<<(cum + 255) / 256, 256, 0, stream>>>(tab, (bf16*)ws, MODE);
    k_prep<<<24, 256, 0, stream>>>(d_in[1], MODE, W1PH, W1PL);

    // ---- per-batch: stage 1 + stage-2 front ----
    for (int b = 0; b < 8; ++b) {
        float* REDb = REDF + (ll)b * 2080;
        k_fused1<<<784, 256, 0, stream>>>(XC, W1PH, W1PL, P1KQVB, P1N1G, P1N1B,
                                          P1W, KP, QP, BIG, REDb, b);
        k_reduce<<<dim3(392, 1), 256, 0, stream>>>(KP, BIG, 64, T1, REDb, 128);
        k_postmlp<<<dim3(784, 1), 256, 0, stream>>>(QP, REDb, BIG, 64, P1PW, P1PB,
            P1N2G, P1N2B, P1M1W, P1M1B, P1M2W, P1M2B, BIG, T1);
        k_unfold576<<<dim3(3136, 1), 256, 0, stream>>>(BIG, 224, 112, P2N1G, P2N1B,
                                                       1, A2, 0, 0);
        k_gemm<<<588, 256, 0, stream>>>(A2, 576, P2KQVW, P2KQVB,
            nullptr, 0, KQV2F, 192, (ll)b * T2, 576, nullptr, 3);
    }

    // ---- batched stage-2 tail (all 8 batches) ----
    k_fusedP2<<<dim3(196, 8), 256, 0, stream>>>(KQV2F, P2W, KP2F, QP2F, REDF, T2);
    k_reduce<<<dim3(98, 8), 256, 0, stream>>>(KP2F, KQV2F + 128, 192, T2, REDF, 128);
    k_postmlp<<<dim3(196, 8), 256, 0, stream>>>(QP2F, REDF, KQV2F + 128, 192,
        P2PW, P2PB, P2N2G, P2N2B, P2M1W, P2M1B, P2M2W, P2M2B, YB2F, T2);

    // ---- epilogue: stage-3 unfold + final projection ----
    const size_t needFull = oBIG + 12845056 + (size_t)25088 * 576 * 2;
    if (ws_size >= needFull) {
        bf16* A3 = (bf16*)(ws + oBIG + 12845056);  // [25088,576]
        k_unfold576<<<dim3(784, 8), 256, 0, stream>>>(
            YB2F, 112, 56, nullptr, nullptr, 0, A3, (ll)T2 * 64, (ll)3136 * 576);
        k_gemm<<<4704, 256, 0, stream>>>(A3, 576, PROJW, PROJB,
            nullptr, 0, d_out, 768, 0, 576, MODE, 12);
    } else {
        for (int c = 0; c < 4; ++c) {
            k_unfold576<<<dim3(784, 2), 256, 0, stream>>>(
                YB2F + (ll)(2 * c) * T2 * 64, 112, 56, nullptr, nullptr, 0,
                A3c, (ll)T2 * 64, (ll)3136 * 576);
            k_gemm<<<1176, 256, 0, stream>>>(A3c, 576, PROJW, PROJB,
                nullptr, 0, d_out, 768, (ll)c * 6272, 576, MODE, 12);
        }
    }
}

// Round 7
// 1005.839 us; speedup vs baseline: 1.0061x; 1.0061x over previous
//
#include <hip/hip_runtime.h>
#include <hip/hip_bf16.h>
#include <math.h>

typedef __hip_bfloat16 bf16;
typedef __attribute__((ext_vector_type(8))) short frag8;
typedef __attribute__((ext_vector_type(4))) float f32x4;
typedef long long ll;

__device__ __forceinline__ float b2f(bf16 v) { return __bfloat162float(v); }
__device__ __forceinline__ bf16 f2b(float v) { return __float2bfloat16(v); }

// pack two floats into one dword of bf16x2
__device__ __forceinline__ unsigned pk2f(float a, float b) {
    union { bf16 h[2]; unsigned u; } c;
    c.h[0] = f2b(a); c.h[1] = f2b(b);
    return c.u;
}
// unpack 8 consecutive bf16 (16B-aligned) into floats
__device__ __forceinline__ void up8(const bf16* p, float* f) {
    const uint4 u = *(const uint4*)p;
    union { unsigned u; bf16 h[2]; } c;
    c.u = u.x; f[0] = b2f(c.h[0]); f[1] = b2f(c.h[1]);
    c.u = u.y; f[2] = b2f(c.h[0]); f[3] = b2f(c.h[1]);
    c.u = u.z; f[4] = b2f(c.h[0]); f[5] = b2f(c.h[1]);
    c.u = u.w; f[6] = b2f(c.h[0]); f[7] = b2f(c.h[1]);
}
// unpack a uint4 of 8 bf16 already in registers
__device__ __forceinline__ void up8u(const uint4 u, float* f) {
    union { unsigned u; bf16 h[2]; } c;
    c.u = u.x; f[0] = b2f(c.h[0]); f[1] = b2f(c.h[1]);
    c.u = u.y; f[2] = b2f(c.h[0]); f[3] = b2f(c.h[1]);
    c.u = u.z; f[4] = b2f(c.h[0]); f[5] = b2f(c.h[1]);
    c.u = u.w; f[6] = b2f(c.h[0]); f[7] = b2f(c.h[1]);
}

#define LN_EPS 1e-5f
#define D_EPS 1e-8f
#define INV_SQRT_M 0.17677669529663687f

// ---------------- dtype sniffer: mode=1 if d_in[0] is float32, 0 if bf16 -------------
__global__ __launch_bounds__(256) void k_sniff(const void* x, int* mode)
{
    __shared__ int cnt;
    if (threadIdx.x == 0) cnt = 0;
    __syncthreads();
    const unsigned short* u = (const unsigned short*)x;
    const unsigned short h = u[2 * threadIdx.x];
    const unsigned int bits = ((unsigned int)h) << 16;
    const float v = __uint_as_float(bits);
    const float a = fabsf(v);
    const bool sane = (h == 0) || (a >= 1e-8f && a <= 1e4f);
    if (!sane) atomicAdd(&cnt, 1);
    __syncthreads();
    if (threadIdx.x == 0) *mode = (cnt > 64) ? 1 : 0;
}

// ---------------- single table-driven convert of all params + x ----------------
struct CvTab { const void* src[28]; int dstOff[28]; int cum[29]; };

__global__ __launch_bounds__(256) void k_convert_all(CvTab tab, bf16* base,
                                                     const int* mode)
{
    const int idx = blockIdx.x * 256 + threadIdx.x;
    if (idx >= tab.cum[28]) return;
    int s = 0;
    while (idx >= tab.cum[s + 1]) ++s;
    const int local = idx - tab.cum[s];
    const float v = (*mode) ? ((const float*)tab.src[s])[local]
                            : b2f(((const bf16*)tab.src[s])[local]);
    base[tab.dstOff[s] + local] = f2b(v);
}

// ---- prologue: pad stage-1 kqv weight [192][27] -> hi/lo bf16 [192][32] ----
__global__ __launch_bounds__(256) void k_prep(
    const void* __restrict__ w1raw, const int* __restrict__ mode,
    bf16* __restrict__ w1ph, bf16* __restrict__ w1pl)
{
    const int idx = blockIdx.x * 256 + threadIdx.x;
    if (idx >= 6144) return;
    const int o = idx >> 5, k = idx & 31;
    float v = 0.f;
    if (k < 27)
        v = (*mode) ? ((const float*)w1raw)[o * 27 + k]
                    : b2f(((const bf16*)w1raw)[o * 27 + k]);
    const bf16 h = f2b(v);
    w1ph[idx] = h;
    w1pl[idx] = f2b(v - b2f(h));
}

// ---- MFMA stage-1 front: unfold27 + LN(27) + kqv GEMM + prm_exp(k,q) ----
__global__ __launch_bounds__(256) void k_fused1(
    const bf16* __restrict__ x, const bf16* __restrict__ w1ph,
    const bf16* __restrict__ w1pl, const bf16* __restrict__ kqvb,
    const bf16* __restrict__ n1g, const bf16* __restrict__ n1b,
    const bf16* __restrict__ pw,
    bf16* __restrict__ KP, bf16* __restrict__ QP, bf16* __restrict__ V,
    float* __restrict__ red, const int b)
{
    // LDS layout (49632 B -> 3 blocks/CU); KPs has its OWN region (no alias).
    __shared__ __align__(16) char smem[49632];
    bf16 (*wps)[72] = (bf16(*)[72])(smem);            // 0..4608
    bf16 (*Ah)[40]  = (bf16(*)[40])(smem + 4608);     // ..9728
    bf16 (*Al)[40]  = (bf16(*)[40])(smem + 9728);     // ..14848
    bf16 (*Th)[72]  = (bf16(*)[72])(smem + 14848);    // ..24064  | alias Vs
    bf16 (*Tl)[72]  = (bf16(*)[72])(smem + 24064);    // ..33280
    bf16 (*Wh)[40]  = (bf16(*)[40])(smem + 33280);    // ..38400
    bf16 (*Wl)[40]  = (bf16(*)[40])(smem + 38400);    // ..43520
    bf16 (*KPs)[40] = (bf16(*)[40])(smem + 43520);    // ..48640 (dedicated)
    bf16 (*Vs)[72]  = (bf16(*)[72])(smem + 14848);    // alias Th (2 barriers apart)
    float* kbs = (float*)(smem + 48640);              // 768
    float* gs  = (float*)(smem + 49408);              // 112
    float* bs  = (float*)(smem + 49520);              // 112

    const int tid = threadIdx.x;
    {
        const int i = tid * 8;
        *(uint4*)(&wps[i >> 6][i & 63]) = *(const uint4*)(pw + i);
    }
    if (tid < 192) kbs[tid] = b2f(kqvb[tid]);
    if (tid < 27) { gs[tid] = b2f(n1g[tid]); bs[tid] = b2f(n1b[tid]); }
    if (blockIdx.x == 0)
        for (int i = tid; i < 2080; i += 256) red[i] = 0.f;

    // ---- unfold + two-pass LN: 4 threads per token (7/7/7/6 values each) ----
    const int tok = tid >> 2, part = tid & 3;
    const int t = blockIdx.x * 64 + tok;
    const int h = t / 224, w = t - h * 224;
    const int d0 = part * 7;
    const int nd = (part == 3) ? 6 : 7;
    float vals[7];
    float s = 0.f;
    #pragma unroll
    for (int q = 0; q < 7; ++q) {
        float val = 0.f;
        if (q < nd) {
            const int d = d0 + q;
            const int c = d / 9, rr = d - c * 9;
            const int pi = rr / 3, pj = rr - pi * 3;
            const int hh = h + pi - 1, ww = w + pj - 1;
            if (hh >= 0 && hh < 224 && ww >= 0 && ww < 224)
                val = b2f(x[((ll)(b * 3 + c) * 224 + hh) * 224 + ww]);
        }
        vals[q] = val; s += val;
    }
    s += __shfl_xor(s, 1, 64);  s += __shfl_xor(s, 2, 64);
    const float mean = s * (1.f / 27.f);
    float s2 = 0.f;
    #pragma unroll
    for (int q = 0; q < 7; ++q) {
        if (q < nd) { const float dd = vals[q] - mean; s2 += dd * dd; }
    }
    s2 += __shfl_xor(s2, 1, 64); s2 += __shfl_xor(s2, 2, 64);
    const float rs = rsqrtf(s2 * (1.f / 27.f) + LN_EPS);
    __syncthreads();   // gs/bs/wps/kbs ready
    #pragma unroll
    for (int q = 0; q < 7; ++q) {
        if (q < nd) {
            const int d = d0 + q;
            const float nv = (vals[q] - mean) * rs * gs[d] + bs[d];
            const bf16 nh = f2b(nv);
            Ah[tok][d] = nh;
            Al[tok][d] = f2b(nv - b2f(nh));
        }
    }
    if (part == 3) {
        #pragma unroll
        for (int d = 27; d < 32; ++d) { Ah[tok][d] = f2b(0.f); Al[tok][d] = f2b(0.f); }
    }

    const int wv = tid >> 6, lane = tid & 63;
    const int l15 = lane & 15;
    const int k8 = (lane >> 4) << 3;
    const int rbase = (lane >> 4) << 2;
    const int srow = tid >> 2;
    const int scol = (tid & 3) << 3;
    const int colg = (tid & 3) << 4;

    float xdK[4], xdQ[4];

    #pragma unroll
    for (int g = 0; g < 3; ++g) {          // 0=K, 1=Q, 2=V
        *(uint4*)(&Wh[srow][scol]) = *(const uint4*)(w1ph + (g * 64 + srow) * 32 + scol);
        *(uint4*)(&Wl[srow][scol]) = *(const uint4*)(w1pl + (g * 64 + srow) * 32 + scol);
        __syncthreads();
        const frag8 ah = *(const frag8*)(&Ah[(wv << 4) + l15][k8]);
        const frag8 al = *(const frag8*)(&Al[(wv << 4) + l15][k8]);
        f32x4 acc[4] = {};
        #pragma unroll
        for (int nt = 0; nt < 4; ++nt) {
            const frag8 bh = *(const frag8*)(&Wh[(nt << 4) + l15][k8]);
            const frag8 bl = *(const frag8*)(&Wl[(nt << 4) + l15][k8]);
            acc[nt] = __builtin_amdgcn_mfma_f32_16x16x32_bf16(ah, bh, acc[nt], 0, 0, 0);
            acc[nt] = __builtin_amdgcn_mfma_f32_16x16x32_bf16(al, bh, acc[nt], 0, 0, 0);
            acc[nt] = __builtin_amdgcn_mfma_f32_16x16x32_bf16(ah, bl, acc[nt], 0, 0, 0);
            acc[nt] = __builtin_amdgcn_mfma_f32_16x16x32_bf16(al, bl, acc[nt], 0, 0, 0);
        }
        float xdp[4] = {0.f, 0.f, 0.f, 0.f};
        #pragma unroll
        for (int nt = 0; nt < 4; ++nt) {
            const int col = (nt << 4) + l15;
            const float bv = kbs[g * 64 + col];
            #pragma unroll
            for (int r = 0; r < 4; ++r) {
                const float tb = acc[nt][r] + bv;
                const int trow = (wv << 4) + rbase + r;
                if (g < 2) {
                    const bf16 th = f2b(tb);
                    Th[trow][col] = th;
                    Tl[trow][col] = f2b(tb - b2f(th));
                    xdp[r] += tb * tb;
                } else {
                    Vs[trow][col] = f2b(tb);
                }
            }
        }
        if (g < 2) {
            #pragma unroll
            for (int r = 0; r < 4; ++r) {
                float v = xdp[r];
                v += __shfl_xor(v, 1, 64); v += __shfl_xor(v, 2, 64);
                v += __shfl_xor(v, 4, 64); v += __shfl_xor(v, 8, 64);
                if (g == 0) xdK[r] = 0.5f * v; else xdQ[r] = 0.5f * v;
            }
        }
        __syncthreads();   // Th/Tl (or Vs) ready; Wh/Wl reads done
        if (g < 2) {
            f32x4 acc2[2] = {};
            #pragma unroll
            for (int k0 = 0; k0 < 64; k0 += 32) {
                const frag8 ath = *(const frag8*)(&Th[(wv << 4) + l15][k8 + k0]);
                const frag8 atl = *(const frag8*)(&Tl[(wv << 4) + l15][k8 + k0]);
                #pragma unroll
                for (int nt = 0; nt < 2; ++nt) {
                    const frag8 bw = *(const frag8*)(&wps[(nt << 4) + l15][k8 + k0]);
                    acc2[nt] = __builtin_amdgcn_mfma_f32_16x16x32_bf16(ath, bw, acc2[nt], 0, 0, 0);
                    acc2[nt] = __builtin_amdgcn_mfma_f32_16x16x32_bf16(atl, bw, acc2[nt], 0, 0, 0);
                }
            }
            #pragma unroll
            for (int nt = 0; nt < 2; ++nt)
                #pragma unroll
                for (int r = 0; r < 4; ++r) {
                    const float xd = (g == 0) ? xdK[r] : xdQ[r];
                    const float p = expf(fminf(acc2[nt][r] - xd, 30.f)) * INV_SQRT_M;
                    KPs[(wv << 4) + rbase + r][(nt << 4) + l15] = f2b(p);
                }
            __syncthreads();   // KPs ready
            bf16* dstP = (g == 0 ? KP : QP) + ((ll)blockIdx.x * 64 + srow) * 32 + scol;
            *(uint4*)dstP = *(const uint4*)(&KPs[srow][scol]);
            __syncthreads();   // KPs reads done before next group reuses it
        } else {
            bf16* dstV = V + ((ll)blockIdx.x * 64 + srow) * 64 + colg;
            *(uint4*)dstV       = *(const uint4*)(&Vs[srow][colg]);
            *(uint4*)(dstV + 8) = *(const uint4*)(&Vs[srow][colg + 8]);
        }
    }
}

// ---- MFMA reduce over tokens: red[n*32+m] += sum_t V[t][n]*KP[t][m]; ksum via ones ----
__global__ __launch_bounds__(256) void k_reduce(
    const bf16* __restrict__ kpB, const bf16* __restrict__ vB, const int vstride,
    const int T, float* __restrict__ redBase, const int chunk)
{
    __shared__ bf16 VT[64][72];   // [n][t]
    __shared__ bf16 KT[32][72];   // [m][t]
    const int bz = blockIdx.y;
    const bf16* kp = kpB + (ll)bz * T * 32;
    const bf16* v  = vB + (ll)bz * T * (ll)vstride;
    float* red = redBase + (ll)bz * 2080;
    const int tid = threadIdx.x;
    const int wv = tid >> 6, lane = tid & 63;
    const int l15 = lane & 15, k8 = (lane >> 4) << 3, rbase = (lane >> 4) << 2;
    const int t0 = blockIdx.x * chunk;

    frag8 ones;
    {
        union { bf16 h; short s; } u; u.h = f2b(1.f);
        #pragma unroll
        for (int i = 0; i < 8; ++i) ones[i] = u.s;
    }

    f32x4 acc[2] = {};
    f32x4 accK[2] = {};

    for (int tt = 0; tt < chunk; tt += 64) {
        const int tb = t0 + tt;
        __syncthreads();
        {
            const int tk = tid >> 2, n0 = (tid & 3) << 4;
            const bf16* src = v + (ll)(tb + tk) * vstride + n0;
            bf16 tmp[16];
            *(uint4*)tmp       = *(const uint4*)src;
            *(uint4*)(tmp + 8) = *(const uint4*)(src + 8);
            #pragma unroll
            for (int j = 0; j < 16; ++j) VT[n0 + j][tk] = tmp[j];
        }
        {
            const int tk = tid >> 2, m0 = (tid & 3) << 3;
            const bf16* src = kp + (ll)(tb + tk) * 32 + m0;
            bf16 tmp[8];
            *(uint4*)tmp = *(const uint4*)src;
            #pragma unroll
            for (int j = 0; j < 8; ++j) KT[m0 + j][tk] = tmp[j];
        }
        __syncthreads();
        #pragma unroll
        for (int ks = 0; ks < 2; ++ks) {
            const frag8 af = *(const frag8*)(&VT[(wv << 4) + l15][k8 + ks * 32]);
            #pragma unroll
            for (int tn = 0; tn < 2; ++tn) {
                const frag8 bfv = *(const frag8*)(&KT[(tn << 4) + l15][k8 + ks * 32]);
                acc[tn] = __builtin_amdgcn_mfma_f32_16x16x32_bf16(af, bfv, acc[tn], 0, 0, 0);
            }
            if (wv == 0) {
                #pragma unroll
                for (int tn = 0; tn < 2; ++tn) {
                    const frag8 bfv = *(const frag8*)(&KT[(tn << 4) + l15][k8 + ks * 32]);
                    accK[tn] = __builtin_amdgcn_mfma_f32_16x16x32_bf16(ones, bfv, accK[tn], 0, 0, 0);
                }
            }
        }
    }
    #pragma unroll
    for (int tn = 0; tn < 2; ++tn) {
        const int m = (tn << 4) + l15;
        #pragma unroll
        for (int r = 0; r < 4; ++r) {
            const int n = (wv << 4) + rbase + r;
            atomicAdd(&red[n * 32 + m], acc[tn][r]);
        }
    }
    if (wv == 0 && (lane >> 4) == 0) {
        #pragma unroll
        for (int tn = 0; tn < 2; ++tn)
            atomicAdd(&red[2048 + (tn << 4) + l15], accK[tn][0]);
    }
}

// ---- merged post-attention + LN + MLP (bit-identical to old k_posta -> k_mlpln) ----
__global__ __launch_bounds__(256) void k_postmlp(
    const bf16* __restrict__ qpB, const float* __restrict__ redBase,
    const bf16* __restrict__ vB, const int vstride,
    const bf16* __restrict__ pw, const bf16* __restrict__ pb,
    const bf16* __restrict__ n2g, const bf16* __restrict__ n2b,
    const bf16* __restrict__ w1, const bf16* __restrict__ b1,
    const bf16* __restrict__ w2, const bf16* __restrict__ b2,
    bf16* outB, const int T)
{
    __shared__ __align__(16) char smem[47232];
    bf16 (*QPs)[40] = (bf16(*)[40])(smem);
    bf16 (*KH)[40]  = (bf16(*)[40])(smem + 5120);
    bf16 (*KL)[40]  = (bf16(*)[40])(smem + 10240);
    float (*Cs)[72] = (float(*)[72])(smem);
    bf16 (*W1s)[72] = (bf16(*)[72])(smem);
    bf16 (*W2s)[72] = (bf16(*)[72])(smem + 9216);
    bf16 (*PWs)[72] = (bf16(*)[72])(smem + 18432);
    bf16 (*Gs)[72]  = (bf16(*)[72])(smem + 18432);
    bf16 (*Y0H)[72] = (bf16(*)[72])(smem + 27648);
    bf16 (*Ys)[72]  = (bf16(*)[72])(smem + 27648);
    bf16 (*Y0L)[72] = (bf16(*)[72])(smem + 36864);
    bf16 (*Hn)[72]  = (bf16(*)[72])(smem + 36864);
    float* invs  = (float*)(smem + 46080);
    float* pbs   = (float*)(smem + 46336);
    float* ksums = (float*)(smem + 46592);
    float* mns   = (float*)(smem + 46720);
    float* rss   = (float*)(smem + 46976);

    const int tid = threadIdx.x;
    const int bz = blockIdx.y;
    const float* red = redBase + (ll)bz * 2080;
    const bf16* qp = qpB + (ll)bz * (ll)T * 32;
    const bf16* v  = vB + (ll)bz * (ll)T * (ll)vstride;
    bf16* out = outB + (ll)bz * (ll)T * 64;
    const ll m0 = (ll)blockIdx.x * 64;

    const int lr = tid >> 2;
    const int lc8 = (tid & 3) << 3;
    const int lc16 = (tid & 3) << 4;

    *(uint4*)(&QPs[lr][lc8]) = *(const uint4*)(qp + (m0 + lr) * 32 + lc8);
    *(uint4*)(&PWs[lr][lc16])     = *(const uint4*)(pw + lr * 64 + lc16);
    *(uint4*)(&PWs[lr][lc16 + 8]) = *(const uint4*)(pw + lr * 64 + lc16 + 8);
    {
        const int i0 = tid * 8;
        const float4 a = *(const float4*)(red + i0);
        const float4 b = *(const float4*)(red + i0 + 4);
        const int n = i0 >> 5, m = i0 & 31;
        float xs[8] = {a.x, a.y, a.z, a.w, b.x, b.y, b.z, b.w};
        #pragma unroll
        for (int k = 0; k < 8; ++k) {
            const bf16 h = f2b(xs[k]);
            KH[n][m + k] = h;
            KL[n][m + k] = f2b(xs[k] - b2f(h));
        }
    }
    if (tid < 32) ksums[tid] = red[2048 + tid];
    if (tid < 64) pbs[tid] = b2f(pb[tid]);
    __syncthreads();

    if (tid < 64) {
        float D = D_EPS;
        #pragma unroll
        for (int m = 0; m < 32; ++m) D += b2f(QPs[tid][m]) * ksums[m];
        invs[tid] = 1.f / D;
    }

    const int wv = tid >> 6, lane = tid & 63;
    const int l15 = lane & 15;
    const int mr = (wv << 4) + l15;
    const int k8 = (lane >> 4) << 3;
    const int rbase = (lane >> 4) << 2;

    f32x4 acc[4] = {};
    {
        const frag8 af = *(const frag8*)(&QPs[mr][k8]);
        #pragma unroll
        for (int tn = 0; tn < 4; ++tn) {
            const int nr = (tn << 4) + l15;
            const frag8 bh = *(const frag8*)(&KH[nr][k8]);
            acc[tn] = __builtin_amdgcn_mfma_f32_16x16x32_bf16(af, bh, acc[tn], 0, 0, 0);
            const frag8 bl = *(const frag8*)(&KL[nr][k8]);
            acc[tn] = __builtin_amdgcn_mfma_f32_16x16x32_bf16(af, bl, acc[tn], 0, 0, 0);
        }
    }
    #pragma unroll
    for (int tn = 0; tn < 4; ++tn) {
        const int n = (tn << 4) + l15;
        #pragma unroll
        for (int r = 0; r < 4; ++r) {
            const float x = acc[tn][r];
            const bf16 h = f2b(x);
            Y0H[(wv << 4) + rbase + r][n] = h;
            Y0L[(wv << 4) + rbase + r][n] = f2b(x - b2f(h));
        }
    }
    __syncthreads();

    f32x4 acc2[4] = {};
    #pragma unroll
    for (int k0 = 0; k0 < 64; k0 += 32) {
        const frag8 ah = *(const frag8*)(&Y0H[mr][k8 + k0]);
        const frag8 al = *(const frag8*)(&Y0L[mr][k8 + k0]);
        #pragma unroll
        for (int tn = 0; tn < 4; ++tn) {
            const frag8 bw = *(const frag8*)(&PWs[(tn << 4) + l15][k8 + k0]);
            acc2[tn] = __builtin_amdgcn_mfma_f32_16x16x32_bf16(ah, bw, acc2[tn], 0, 0, 0);
            acc2[tn] = __builtin_amdgcn_mfma_f32_16x16x32_bf16(al, bw, acc2[tn], 0, 0, 0);
        }
    }
    #pragma unroll
    for (int tn = 0; tn < 4; ++tn) {
        const int n = (tn << 4) + l15;
        #pragma unroll
        for (int r = 0; r < 4; ++r) {
            const int row = (wv << 4) + rbase + r;
            Cs[row][n] = acc2[tn][r] * invs[row] + pbs[n];
        }
    }
    __syncthreads();

    {
        const int row = tid >> 2;
        const bf16* vsrc = v + (m0 + row) * (ll)vstride + lc16;
        #pragma unroll
        for (int hh = 0; hh < 2; ++hh) {
            float vv[8];
            up8(vsrc + hh * 8, vv);
            const float* cp = &Cs[row][lc16 + hh * 8];
            uint4 st;
            st.x = pk2f(cp[0] + vv[0], cp[1] + vv[1]);
            st.y = pk2f(cp[2] + vv[2], cp[3] + vv[3]);
            st.z = pk2f(cp[4] + vv[4], cp[5] + vv[5]);
            st.w = pk2f(cp[6] + vv[6], cp[7] + vv[7]);
            *(uint4*)(&Ys[row][lc16 + hh * 8]) = st;
        }
    }
    __syncthreads();

    if (tid < 64) {
        float s = 0.f, s2 = 0.f;
        #pragma unroll
        for (int n = 0; n < 64; ++n) { const float vv = b2f(Ys[tid][n]); s += vv; s2 += vv * vv; }
        const float mn = s * (1.f / 64.f);
        const float var = fmaxf(s2 * (1.f / 64.f) - mn * mn, 0.f);
        mns[tid] = mn; rss[tid] = rsqrtf(var + LN_EPS);
    }
    *(uint4*)(&W1s[lr][lc16])     = *(const uint4*)(w1 + lr * 64 + lc16);
    *(uint4*)(&W1s[lr][lc16 + 8]) = *(const uint4*)(w1 + lr * 64 + lc16 + 8);
    *(uint4*)(&W2s[lr][lc16])     = *(const uint4*)(w2 + lr * 64 + lc16);
    *(uint4*)(&W2s[lr][lc16 + 8]) = *(const uint4*)(w2 + lr * 64 + lc16 + 8);
    __syncthreads();

    for (int i = tid; i < 4096; i += 256) {
        const int r = i >> 6, c = i & 63;
        Hn[r][c] = f2b((b2f(Ys[r][c]) - mns[r]) * rss[r] * b2f(n2g[c]) + b2f(n2b[c]));
    }
    __syncthreads();

    f32x4 accm[4] = {};
    #pragma unroll
    for (int k0 = 0; k0 < 64; k0 += 32) {
        const frag8 af = *(const frag8*)(&Hn[mr][k8 + k0]);
        #pragma unroll
        for (int tn = 0; tn < 4; ++tn) {
            const frag8 bfv = *(const frag8*)(&W1s[(tn << 4) + l15][k8 + k0]);
            accm[tn] = __builtin_amdgcn_mfma_f32_16x16x32_bf16(af, bfv, accm[tn], 0, 0, 0);
        }
    }
    #pragma unroll
    for (int tn = 0; tn < 4; ++tn) {
        const int n = (tn << 4) + l15;
        const float bv = b2f(b1[n]);
        #pragma unroll
        for (int r = 0; r < 4; ++r) {
            float vg = accm[tn][r] + bv;
            vg = 0.5f * vg * (1.f + erff(vg * 0.70710678118654752f));
            Gs[(wv << 4) + rbase + r][n] = f2b(vg);
        }
    }
    __syncthreads();

    f32x4 accn[4] = {};
    #pragma unroll
    for (int k0 = 0; k0 < 64; k0 += 32) {
        const frag8 af = *(const frag8*)(&Gs[mr][k8 + k0]);
        #pragma unroll
        for (int tn = 0; tn < 4; ++tn) {
            const frag8 bfv = *(const frag8*)(&W2s[(tn << 4) + l15][k8 + k0]);
            accn[tn] = __builtin_amdgcn_mfma_f32_16x16x32_bf16(af, bfv, accn[tn], 0, 0, 0);
        }
    }
    #pragma unroll
    for (int tn = 0; tn < 4; ++tn) {
        const int n = (tn << 4) + l15;
        const float bv = b2f(b2[n]);
        #pragma unroll
        for (int r = 0; r < 4; ++r)
            Hn[(wv << 4) + rbase + r][n] = f2b(accn[tn][r] + bv);
    }
    __syncthreads();

    {
        const int row = tid >> 2;
        bf16* dst = out + (m0 + row) * 64 + lc16;
        #pragma unroll
        for (int hh = 0; hh < 2; ++hh) {
            float sv[8], rv[8];
            up8(&Hn[row][lc16 + hh * 8], sv);
            up8(&Ys[row][lc16 + hh * 8], rv);
            uint4 st;
            st.x = pk2f(sv[0] + rv[0], sv[1] + rv[1]);
            st.y = pk2f(sv[2] + rv[2], sv[3] + rv[3]);
            st.z = pk2f(sv[4] + rv[4], sv[5] + rv[5]);
            st.w = pk2f(sv[6] + rv[6], sv[7] + rv[7]);
            *(uint4*)(dst + hh * 8) = st;
        }
    }
}

// ---- unfold 3x3 s2 p1, token-major [Hin*Hin,64] -> [Ho*Ho,576] (+opt LN) ----
__global__ __launch_bounds__(256) void k_unfold576(
    const bf16* __restrict__ in, const int Hin, const int Ho,
    const bf16* __restrict__ g, const bf16* __restrict__ bb,
    const int do_ln, bf16* __restrict__ A,
    const ll inBStride, const ll outBStride)
{
    in += (ll)blockIdx.y * inBStride;
    A  += (ll)blockIdx.y * outBStride;
    const int t = blockIdx.x * 4 + (threadIdx.x >> 6);
    const int l = threadIdx.x & 63;
    const int ho = t / Ho, wo = t - ho * Ho;
    float vals[9];
    float s = 0.f;
    #pragma unroll
    for (int r = 0; r < 9; ++r) {
        const int d = l + (r << 6);
        const int c = d / 9;
        const int rr = d - c * 9;
        const int i = rr / 3, j = rr - i * 3;
        const int hh = 2 * ho + i - 1, ww = 2 * wo + j - 1;
        float val = 0.f;
        if (hh >= 0 && hh < Hin && ww >= 0 && ww < Hin)
            val = b2f(in[((ll)hh * Hin + ww) * 64 + c]);
        vals[r] = val; s += val;
    }
    bf16* out = A + (ll)t * 576;
    if (do_ln) {
        #pragma unroll
        for (int o = 32; o > 0; o >>= 1) s += __shfl_xor(s, o, 64);
        const float mean = s * (1.f / 576.f);
        float s2 = 0.f;
        #pragma unroll
        for (int r = 0; r < 9; ++r) { const float dd = vals[r] - mean; s2 += dd * dd; }
        #pragma unroll
        for (int o = 32; o > 0; o >>= 1) s2 += __shfl_xor(s2, o, 64);
        const float rs = rsqrtf(s2 * (1.f / 576.f) + LN_EPS);
        #pragma unroll
        for (int r = 0; r < 9; ++r) {
            const int d = l + (r << 6);
            out[d] = f2b((vals[r] - mean) * rs * b2f(g[d]) + b2f(bb[d]));
        }
    } else {
        #pragma unroll
        for (int r = 0; r < 9; ++r) out[l + (r << 6)] = f2b(vals[r]);
    }
}

// ---- MFMA bf16 GEMM: C[M,N] = A@W^T + bias (+res); BM=128 double-buffered ----
// 1-D grid, bijective XCD-chunk swizzle (n fastest -> per-XCD A-window fits L2).
// Each wave owns two 16-row m-frags: 8 MFMAs per barrier. Per-output-element
// accumulation order identical to the BM=64 version (bit-identical numerics).
__global__ __launch_bounds__(256) void k_gemm(
    const bf16* __restrict__ A, const int lda,
    const bf16* __restrict__ W,
    const bf16* __restrict__ bias,
    const bf16* res, const int ldres,
    void* C, const int ldc, const ll mOff,
    const int K, const int* outm, const int gridN)
{
    // LDS 30720 B -> 5 blocks/CU. Cs (bf16 epilogue) aliases dead As.
    __shared__ __align__(16) char smem[30720];
    bf16 (*As)[128][40] = (bf16(*)[128][40])smem;            // [2][128][40] 20480
    bf16 (*Bs)[64][40]  = (bf16(*)[64][40])(smem + 20480);   // [2][64][40] 10240
    bf16 (*Cs)[72]      = (bf16(*)[72])smem;                 // [128][72] 18432 alias

    const int nwg = gridDim.x;
    const int orig = blockIdx.x;
    const int xcd = orig & 7;
    const int q = nwg >> 3, r = nwg & 7;
    const int wgid = (xcd < r ? xcd * (q + 1) : r * (q + 1) + (xcd - r) * q)
                     + (orig >> 3);
    const int mTile = wgid / gridN;
    const int nTile = wgid - mTile * gridN;
    const ll m0 = (ll)mTile * 128;
    const int n0 = nTile * 64;

    const int tid = threadIdx.x;
    const int wv = tid >> 6, lane = tid & 63, l15 = lane & 15;
    const int k8 = (lane >> 4) << 3;
    const int rbase = (lane >> 4) << 2;
    const int mr0 = (wv << 5) + l15;          // wave owns rows [wv*32, wv*32+32)
    const int ar = tid >> 1, ac = (tid & 1) << 4;
    const int br = tid >> 2, bc = (tid & 3) << 3;
    const bf16* Ag = A + (m0 + ar) * (ll)lda + ac;
    const bf16* Wg = W + (ll)(n0 + br) * K + bc;

    f32x4 acc[2][4] = {};
    uint4 a0 = *(const uint4*)(Ag);
    uint4 a1 = *(const uint4*)(Ag + 8);
    uint4 b0 = *(const uint4*)(Wg);
    *(uint4*)(&As[0][ar][ac])     = a0;
    *(uint4*)(&As[0][ar][ac + 8]) = a1;
    *(uint4*)(&Bs[0][br][bc])     = b0;
    int curb = 0;
    __syncthreads();
    for (int k0 = 0; k0 < K; k0 += 32) {
        const bool nxt = (k0 + 32 < K);
        if (nxt) {
            a0 = *(const uint4*)(Ag + k0 + 32);
            a1 = *(const uint4*)(Ag + k0 + 40);
            b0 = *(const uint4*)(Wg + k0 + 32);
        }
        const frag8 af0 = *(const frag8*)(&As[curb][mr0][k8]);
        const frag8 af1 = *(const frag8*)(&As[curb][mr0 + 16][k8]);
        #pragma unroll
        for (int tn = 0; tn < 4; ++tn) {
            const frag8 bfv = *(const frag8*)(&Bs[curb][(tn << 4) + l15][k8]);
            acc[0][tn] = __builtin_amdgcn_mfma_f32_16x16x32_bf16(af0, bfv, acc[0][tn], 0, 0, 0);
            acc[1][tn] = __builtin_amdgcn_mfma_f32_16x16x32_bf16(af1, bfv, acc[1][tn], 0, 0, 0);
        }
        if (nxt) {
            *(uint4*)(&As[curb ^ 1][ar][ac])     = a0;
            *(uint4*)(&As[curb ^ 1][ar][ac + 8]) = a1;
            *(uint4*)(&Bs[curb ^ 1][br][bc])     = b0;
        }
        __syncthreads();
        curb ^= 1;
    }
    const int om = outm ? *outm : 0;
    if (om) {   // fp32 output: direct stores (proven best; no LDS round-trip)
        #pragma unroll
        for (int mi = 0; mi < 2; ++mi)
            #pragma unroll
            for (int tn = 0; tn < 4; ++tn) {
                const int n = n0 + (tn << 4) + l15;
                const float bv = bias ? b2f(bias[n]) : 0.f;
                #pragma unroll
                for (int rr2 = 0; rr2 < 4; ++rr2) {
                    const ll m = m0 + (wv << 5) + (mi << 4) + rbase + rr2;
                    float v = acc[mi][tn][rr2] + bv;
                    if (res) v += b2f(res[m * (ll)ldres + n]);
                    ((float*)C)[(m + mOff) * (ll)ldc + n] = v;
                }
            }
        return;
    }
    #pragma unroll
    for (int mi = 0; mi < 2; ++mi)
        #pragma unroll
        for (int tn = 0; tn < 4; ++tn) {
            const int nl = (tn << 4) + l15;
            const float bv = bias ? b2f(bias[n0 + nl]) : 0.f;
            #pragma unroll
            for (int rr2 = 0; rr2 < 4; ++rr2) {
                const ll m = m0 + (wv << 5) + (mi << 4) + rbase + rr2;
                float v = acc[mi][tn][rr2] + bv;
                if (res) v += b2f(res[m * (ll)ldres + n0 + nl]);
                Cs[(wv << 5) + (mi << 4) + rbase + rr2][nl] = f2b(v);
            }
        }
    __syncthreads();
    const int row = tid >> 2;
    const int colg = (tid & 3) << 4;
    #pragma unroll
    for (int h2 = 0; h2 < 2; ++h2) {
        bf16* dst = (bf16*)C + (m0 + mOff + row + h2 * 64) * (ll)ldc + n0 + colg;
        *(uint4*)dst       = *(const uint4*)(&Cs[row + h2 * 64][colg]);
        *(uint4*)(dst + 8) = *(const uint4*)(&Cs[row + h2 * 64][colg + 8]);
    }
}

// ---- MFMA prm_exp for stage-2 (k and q passes) + RED zeroing ----
__global__ __launch_bounds__(256) void k_fusedP2(
    const bf16* __restrict__ kqv, const bf16* __restrict__ pw,
    bf16* __restrict__ KP, bf16* __restrict__ QP,
    float* __restrict__ redBase, const int T)
{
    __shared__ __align__(16) char smem[19200];
    bf16 (*Ks)[72]  = (bf16(*)[72])(smem);            // 9216
    bf16 (*wps)[72] = (bf16(*)[72])(smem + 9216);     // 4608
    bf16 (*KPs)[40] = (bf16(*)[40])(smem + 13824);    // 5120
    float* xds = (float*)(smem + 18944);              // 256

    const int tid = threadIdx.x;
    const int bz = blockIdx.y;
    {
        const int i = tid * 8;
        *(uint4*)(&wps[i >> 6][i & 63]) = *(const uint4*)(pw + i);
    }
    if (blockIdx.x == 0) {
        float* red = redBase + (ll)bz * 2080;
        for (int i = tid; i < 2080; i += 256) red[i] = 0.f;
    }
    const ll gt0 = (ll)bz * T + (ll)blockIdx.x * 64;
    const int srow = tid >> 2;
    const int colg = (tid & 3) << 4;
    const int scol = (tid & 3) << 3;
    const int wv = tid >> 6, lane = tid & 63;
    const int l15 = lane & 15, k8 = (lane >> 4) << 3, rbase = (lane >> 4) << 2;

    #pragma unroll
    for (int p = 0; p < 2; ++p) {          // 0 = k pass, 1 = q pass
        const bf16* src = kqv + (gt0 + srow) * 192 + p * 64 + colg;
        const uint4 u0 = *(const uint4*)src;
        const uint4 u1 = *(const uint4*)(src + 8);
        *(uint4*)(&Ks[srow][colg])     = u0;
        *(uint4*)(&Ks[srow][colg + 8]) = u1;
        float f0[8], f1[8];
        up8u(u0, f0); up8u(u1, f1);
        float s2 = 0.f;
        #pragma unroll
        for (int k = 0; k < 8; ++k) s2 += f0[k] * f0[k] + f1[k] * f1[k];
        s2 += __shfl_xor(s2, 1, 64); s2 += __shfl_xor(s2, 2, 64);
        if ((tid & 3) == 0) xds[srow] = 0.5f * s2;
        __syncthreads();
        f32x4 acc2[2] = {};
        #pragma unroll
        for (int k0 = 0; k0 < 64; k0 += 32) {
            const frag8 af = *(const frag8*)(&Ks[(wv << 4) + l15][k8 + k0]);
            #pragma unroll
            for (int nt = 0; nt < 2; ++nt) {
                const frag8 bw = *(const frag8*)(&wps[(nt << 4) + l15][k8 + k0]);
                acc2[nt] = __builtin_amdgcn_mfma_f32_16x16x32_bf16(af, bw, acc2[nt], 0, 0, 0);
            }
        }
        #pragma unroll
        for (int nt = 0; nt < 2; ++nt)
            #pragma unroll
            for (int r = 0; r < 4; ++r) {
                const int trow = (wv << 4) + rbase + r;
                const float pv = expf(fminf(acc2[nt][r] - xds[trow], 30.f)) * INV_SQRT_M;
                KPs[trow][(nt << 4) + l15] = f2b(pv);
            }
        __syncthreads();
        bf16* dst = (p == 0 ? KP : QP) + (gt0 + srow) * 32 + scol;
        *(uint4*)dst = *(const uint4*)(&KPs[srow][scol]);
        __syncthreads();   // before next pass overwrites Ks/xds/KPs
    }
}

extern "C" void kernel_launch(void* const* d_in, const int* in_sizes, int n_in,
                              void* d_out, int out_size, void* d_ws, size_t ws_size,
                              hipStream_t stream)
{
    (void)in_sizes; (void)n_in; (void)out_size;
    const int T1 = 50176, T2 = 12544;
    char* ws = (char*)d_ws;

    // ---- cursor-based workspace allocation ----
    size_t cur = 0;
    auto alloc = [&](size_t bytes) {
        size_t r = cur; cur += (bytes + 127) & ~(size_t)127; return r;
    };
    static const int segIdx[28] = {0, 2, 3, 4, 5, 6, 7, 8, 9, 10, 11, 12, 13,
                                   14, 15, 16, 17, 18, 19, 20, 21, 22, 23, 24, 25, 26, 27, 28};
    static const int segN[28] = {1204224, 192, 4096, 64, 27, 27, 64, 64, 4096, 64, 4096, 64, 2048,
                                 110592, 192, 4096, 64, 576, 576, 64, 64, 4096, 64, 4096, 64, 2048,
                                 442368, 768};
    size_t segOff[28];
    for (int i = 0; i < 28; ++i) segOff[i] = alloc((size_t)segN[i] * 2);
    const size_t oMODE = alloc(256);
    const size_t oRED  = alloc(66560);             // 8 x 2080 fp32
    const size_t oW1P  = alloc(24576);             // hi/lo padded [192][32] bf16
    const size_t oBIG  = alloc(6422528);           // [T1,64]
    const size_t oKP   = alloc(3211264);           // [T1,32]
    const size_t oQP   = alloc(3211264);           // [T1,32]
    (void)oQP;

    bf16* P[28];
    for (int i = 0; i < 28; ++i) P[i] = (bf16*)(ws + segOff[i]);
    bf16* XC = P[0];
    bf16 *P1KQVB = P[1], *P1PW = P[2], *P1PB = P[3], *P1N1G = P[4], *P1N1B = P[5];
    bf16 *P1N2G = P[6], *P1N2B = P[7], *P1M1W = P[8], *P1M1B = P[9], *P1M2W = P[10];
    bf16 *P1M2B = P[11], *P1W = P[12];
    bf16 *P2KQVW = P[13], *P2KQVB = P[14], *P2PW = P[15], *P2PB = P[16];
    bf16 *P2N1G = P[17], *P2N1B = P[18], *P2N2G = P[19], *P2N2B = P[20];
    bf16 *P2M1W = P[21], *P2M1B = P[22], *P2M2W = P[23], *P2M2B = P[24], *P2W = P[25];
    bf16 *PROJW = P[26], *PROJB = P[27];

    int*   MODE = (int*)(ws + oMODE);
    float* REDF = (float*)(ws + oRED);
    bf16*  W1PH = (bf16*)(ws + oW1P);
    bf16*  W1PL = (bf16*)(ws + oW1P + 12288);
    bf16*  BIG  = (bf16*)(ws + oBIG);              // stage-1 V/Y/OUT (in-place chain)
    bf16*  KP   = (bf16*)(ws + oKP);
    bf16*  QP   = (bf16*)(ws + oKP + 3211264);
    bf16*  A2   = (bf16*)(ws + oKP);               // [T2,576] over dead KP/QP
    bf16*  KQV2F = (bf16*)d_out;                   // [8*T2,192] scratch in d_out
    bf16*  KP2F  = (bf16*)(ws + oKP);              // [8*T2,32]
    bf16*  QP2F  = (bf16*)(ws + oKP + 6422528);    // [8*T2,32]
    bf16*  YB2F  = (bf16*)(ws + oBIG);             // [8*T2,64] (over BIG, dead)
    bf16*  A3c   = (bf16*)(ws + oBIG + 12845056);  // [6272,576] chunk

    // ---- prologue ----
    k_sniff<<<1, 256, 0, stream>>>(d_in[0], MODE);
    CvTab tab;
    int cum = 0;
    for (int i = 0; i < 28; ++i) {
        tab.src[i] = d_in[segIdx[i]];
        tab.dstOff[i] = (int)(segOff[i] / 2);
        tab.cum[i] = cum;
        cum += segN[i];
    }
    tab.cum[28] = cum;
    k_convert_all<<<(cum + 255) / 256, 256, 0, stream>>>(tab, (bf16*)ws, MODE);
    k_prep<<<24, 256, 0, stream>>>(d_in[1], MODE, W1PH, W1PL);

    // ---- per-batch: stage 1 + stage-2 front ----
    for (int b = 0; b < 8; ++b) {
        float* REDb = REDF + (ll)b * 2080;
        k_fused1<<<784, 256, 0, stream>>>(XC, W1PH, W1PL, P1KQVB, P1N1G, P1N1B,
                                          P1W, KP, QP, BIG, REDb, b);
        k_reduce<<<dim3(392, 1), 256, 0, stream>>>(KP, BIG, 64, T1, REDb, 128);
        k_postmlp<<<dim3(784, 1), 256, 0, stream>>>(QP, REDb, BIG, 64, P1PW, P1PB,
            P1N2G, P1N2B, P1M1W, P1M1B, P1M2W, P1M2B, BIG, T1);
        k_unfold576<<<dim3(3136, 1), 256, 0, stream>>>(BIG, 224, 112, P2N1G, P2N1B,
                                                       1, A2, 0, 0);
        k_gemm<<<294, 256, 0, stream>>>(A2, 576, P2KQVW, P2KQVB,
            nullptr, 0, KQV2F, 192, (ll)b * T2, 576, nullptr, 3);
    }

    // ---- batched stage-2 tail (all 8 batches) ----
    k_fusedP2<<<dim3(196, 8), 256, 0, stream>>>(KQV2F, P2W, KP2F, QP2F, REDF, T2);
    k_reduce<<<dim3(98, 8), 256, 0, stream>>>(KP2F, KQV2F + 128, 192, T2, REDF, 128);
    k_postmlp<<<dim3(196, 8), 256, 0, stream>>>(QP2F, REDF, KQV2F + 128, 192,
        P2PW, P2PB, P2N2G, P2N2B, P2M1W, P2M1B, P2M2W, P2M2B, YB2F, T2);

    // ---- epilogue: stage-3 unfold + final projection ----
    const size_t needFull = oBIG + 12845056 + (size_t)25088 * 576 * 2;
    if (ws_size >= needFull) {
        bf16* A3 = (bf16*)(ws + oBIG + 12845056);  // [25088,576]
        k_unfold576<<<dim3(784, 8), 256, 0, stream>>>(
            YB2F, 112, 56, nullptr, nullptr, 0, A3, (ll)T2 * 64, (ll)3136 * 576);
        k_gemm<<<2352, 256, 0, stream>>>(A3, 576, PROJW, PROJB,
            nullptr, 0, d_out, 768, 0, 576, MODE, 12);
    } else {
        for (int c = 0; c < 4; ++c) {
            k_unfold576<<<dim3(784, 2), 256, 0, stream>>>(
                YB2F + (ll)(2 * c) * T2 * 64, 112, 56, nullptr, nullptr, 0,
                A3c, (ll)T2 * 64, (ll)3136 * 576);
            k_gemm<<<588, 256, 0, stream>>>(A3c, 576, PROJW, PROJB,
                nullptr, 0, d_out, 768, (ll)c * 6272, 576, MODE, 12);
        }
    }
}

// Round 8
// 960.534 us; speedup vs baseline: 1.0536x; 1.0472x over previous
//
#include <hip/hip_runtime.h>
#include <hip/hip_bf16.h>
#include <math.h>

typedef __hip_bfloat16 bf16;
typedef __attribute__((ext_vector_type(8))) short frag8;
typedef __attribute__((ext_vector_type(4))) float f32x4;
typedef long long ll;

__device__ __forceinline__ float b2f(bf16 v) { return __bfloat162float(v); }
__device__ __forceinline__ bf16 f2b(float v) { return __float2bfloat16(v); }

// pack two floats into one dword of bf16x2
__device__ __forceinline__ unsigned pk2f(float a, float b) {
    union { bf16 h[2]; unsigned u; } c;
    c.h[0] = f2b(a); c.h[1] = f2b(b);
    return c.u;
}
// unpack 8 consecutive bf16 (16B-aligned) into floats
__device__ __forceinline__ void up8(const bf16* p, float* f) {
    const uint4 u = *(const uint4*)p;
    union { unsigned u; bf16 h[2]; } c;
    c.u = u.x; f[0] = b2f(c.h[0]); f[1] = b2f(c.h[1]);
    c.u = u.y; f[2] = b2f(c.h[0]); f[3] = b2f(c.h[1]);
    c.u = u.z; f[4] = b2f(c.h[0]); f[5] = b2f(c.h[1]);
    c.u = u.w; f[6] = b2f(c.h[0]); f[7] = b2f(c.h[1]);
}
// unpack a uint4 of 8 bf16 already in registers
__device__ __forceinline__ void up8u(const uint4 u, float* f) {
    union { unsigned u; bf16 h[2]; } c;
    c.u = u.x; f[0] = b2f(c.h[0]); f[1] = b2f(c.h[1]);
    c.u = u.y; f[2] = b2f(c.h[0]); f[3] = b2f(c.h[1]);
    c.u = u.z; f[4] = b2f(c.h[0]); f[5] = b2f(c.h[1]);
    c.u = u.w; f[6] = b2f(c.h[0]); f[7] = b2f(c.h[1]);
}

#define LN_EPS 1e-5f
#define D_EPS 1e-8f
#define INV_SQRT_M 0.17677669529663687f

// ---------------- dtype sniffer: mode=1 if d_in[0] is float32, 0 if bf16 -------------
__global__ __launch_bounds__(256) void k_sniff(const void* x, int* mode)
{
    __shared__ int cnt;
    if (threadIdx.x == 0) cnt = 0;
    __syncthreads();
    const unsigned short* u = (const unsigned short*)x;
    const unsigned short h = u[2 * threadIdx.x];
    const unsigned int bits = ((unsigned int)h) << 16;
    const float v = __uint_as_float(bits);
    const float a = fabsf(v);
    const bool sane = (h == 0) || (a >= 1e-8f && a <= 1e4f);
    if (!sane) atomicAdd(&cnt, 1);
    __syncthreads();
    if (threadIdx.x == 0) *mode = (cnt > 64) ? 1 : 0;
}

// ---------------- single table-driven convert of all params + x ----------------
struct CvTab { const void* src[28]; int dstOff[28]; int cum[29]; };

__global__ __launch_bounds__(256) void k_convert_all(CvTab tab, bf16* base,
                                                     const int* mode)
{
    const int idx = blockIdx.x * 256 + threadIdx.x;
    if (idx >= tab.cum[28]) return;
    int s = 0;
    while (idx >= tab.cum[s + 1]) ++s;
    const int local = idx - tab.cum[s];
    const float v = (*mode) ? ((const float*)tab.src[s])[local]
                            : b2f(((const bf16*)tab.src[s])[local]);
    base[tab.dstOff[s] + local] = f2b(v);
}

// ---- prologue: pad stage-1 kqv weight [192][27] -> hi/lo bf16 [192][32] ----
__global__ __launch_bounds__(256) void k_prep(
    const void* __restrict__ w1raw, const int* __restrict__ mode,
    bf16* __restrict__ w1ph, bf16* __restrict__ w1pl)
{
    const int idx = blockIdx.x * 256 + threadIdx.x;
    if (idx >= 6144) return;
    const int o = idx >> 5, k = idx & 31;
    float v = 0.f;
    if (k < 27)
        v = (*mode) ? ((const float*)w1raw)[o * 27 + k]
                    : b2f(((const bf16*)w1raw)[o * 27 + k]);
    const bf16 h = f2b(v);
    w1ph[idx] = h;
    w1pl[idx] = f2b(v - b2f(h));
}

// ---- MFMA stage-1 front: unfold27 + LN(27) + kqv GEMM + prm_exp(k,q) ----
__global__ __launch_bounds__(256) void k_fused1(
    const bf16* __restrict__ x, const bf16* __restrict__ w1ph,
    const bf16* __restrict__ w1pl, const bf16* __restrict__ kqvb,
    const bf16* __restrict__ n1g, const bf16* __restrict__ n1b,
    const bf16* __restrict__ pw,
    bf16* __restrict__ KP, bf16* __restrict__ QP, bf16* __restrict__ V,
    float* __restrict__ red, const int b)
{
    // LDS layout (49632 B -> 3 blocks/CU); KPs has its OWN region (no alias).
    __shared__ __align__(16) char smem[49632];
    bf16 (*wps)[72] = (bf16(*)[72])(smem);            // 0..4608
    bf16 (*Ah)[40]  = (bf16(*)[40])(smem + 4608);     // ..9728
    bf16 (*Al)[40]  = (bf16(*)[40])(smem + 9728);     // ..14848
    bf16 (*Th)[72]  = (bf16(*)[72])(smem + 14848);    // ..24064  | alias Vs
    bf16 (*Tl)[72]  = (bf16(*)[72])(smem + 24064);    // ..33280
    bf16 (*Wh)[40]  = (bf16(*)[40])(smem + 33280);    // ..38400
    bf16 (*Wl)[40]  = (bf16(*)[40])(smem + 38400);    // ..43520
    bf16 (*KPs)[40] = (bf16(*)[40])(smem + 43520);    // ..48640 (dedicated)
    bf16 (*Vs)[72]  = (bf16(*)[72])(smem + 14848);    // alias Th (2 barriers apart)
    float* kbs = (float*)(smem + 48640);              // 768
    float* gs  = (float*)(smem + 49408);              // 112
    float* bs  = (float*)(smem + 49520);              // 112

    const int tid = threadIdx.x;
    {
        const int i = tid * 8;
        *(uint4*)(&wps[i >> 6][i & 63]) = *(const uint4*)(pw + i);
    }
    if (tid < 192) kbs[tid] = b2f(kqvb[tid]);
    if (tid < 27) { gs[tid] = b2f(n1g[tid]); bs[tid] = b2f(n1b[tid]); }
    if (blockIdx.x == 0)
        for (int i = tid; i < 2080; i += 256) red[i] = 0.f;

    // ---- unfold + two-pass LN: 4 threads per token (7/7/7/6 values each) ----
    const int tok = tid >> 2, part = tid & 3;
    const int t = blockIdx.x * 64 + tok;
    const int h = t / 224, w = t - h * 224;
    const int d0 = part * 7;
    const int nd = (part == 3) ? 6 : 7;
    float vals[7];
    float s = 0.f;
    #pragma unroll
    for (int q = 0; q < 7; ++q) {
        float val = 0.f;
        if (q < nd) {
            const int d = d0 + q;
            const int c = d / 9, rr = d - c * 9;
            const int pi = rr / 3, pj = rr - pi * 3;
            const int hh = h + pi - 1, ww = w + pj - 1;
            if (hh >= 0 && hh < 224 && ww >= 0 && ww < 224)
                val = b2f(x[((ll)(b * 3 + c) * 224 + hh) * 224 + ww]);
        }
        vals[q] = val; s += val;
    }
    s += __shfl_xor(s, 1, 64);  s += __shfl_xor(s, 2, 64);
    const float mean = s * (1.f / 27.f);
    float s2 = 0.f;
    #pragma unroll
    for (int q = 0; q < 7; ++q) {
        if (q < nd) { const float dd = vals[q] - mean; s2 += dd * dd; }
    }
    s2 += __shfl_xor(s2, 1, 64); s2 += __shfl_xor(s2, 2, 64);
    const float rs = rsqrtf(s2 * (1.f / 27.f) + LN_EPS);
    __syncthreads();   // gs/bs/wps/kbs ready
    #pragma unroll
    for (int q = 0; q < 7; ++q) {
        if (q < nd) {
            const int d = d0 + q;
            const float nv = (vals[q] - mean) * rs * gs[d] + bs[d];
            const bf16 nh = f2b(nv);
            Ah[tok][d] = nh;
            Al[tok][d] = f2b(nv - b2f(nh));
        }
    }
    if (part == 3) {
        #pragma unroll
        for (int d = 27; d < 32; ++d) { Ah[tok][d] = f2b(0.f); Al[tok][d] = f2b(0.f); }
    }

    const int wv = tid >> 6, lane = tid & 63;
    const int l15 = lane & 15;
    const int k8 = (lane >> 4) << 3;
    const int rbase = (lane >> 4) << 2;
    const int srow = tid >> 2;
    const int scol = (tid & 3) << 3;
    const int colg = (tid & 3) << 4;

    float xdK[4], xdQ[4];

    #pragma unroll
    for (int g = 0; g < 3; ++g) {          // 0=K, 1=Q, 2=V
        *(uint4*)(&Wh[srow][scol]) = *(const uint4*)(w1ph + (g * 64 + srow) * 32 + scol);
        *(uint4*)(&Wl[srow][scol]) = *(const uint4*)(w1pl + (g * 64 + srow) * 32 + scol);
        __syncthreads();
        const frag8 ah = *(const frag8*)(&Ah[(wv << 4) + l15][k8]);
        const frag8 al = *(const frag8*)(&Al[(wv << 4) + l15][k8]);
        f32x4 acc[4] = {};
        #pragma unroll
        for (int nt = 0; nt < 4; ++nt) {
            const frag8 bh = *(const frag8*)(&Wh[(nt << 4) + l15][k8]);
            const frag8 bl = *(const frag8*)(&Wl[(nt << 4) + l15][k8]);
            acc[nt] = __builtin_amdgcn_mfma_f32_16x16x32_bf16(ah, bh, acc[nt], 0, 0, 0);
            acc[nt] = __builtin_amdgcn_mfma_f32_16x16x32_bf16(al, bh, acc[nt], 0, 0, 0);
            acc[nt] = __builtin_amdgcn_mfma_f32_16x16x32_bf16(ah, bl, acc[nt], 0, 0, 0);
            acc[nt] = __builtin_amdgcn_mfma_f32_16x16x32_bf16(al, bl, acc[nt], 0, 0, 0);
        }
        float xdp[4] = {0.f, 0.f, 0.f, 0.f};
        #pragma unroll
        for (int nt = 0; nt < 4; ++nt) {
            const int col = (nt << 4) + l15;
            const float bv = kbs[g * 64 + col];
            #pragma unroll
            for (int r = 0; r < 4; ++r) {
                const float tb = acc[nt][r] + bv;
                const int trow = (wv << 4) + rbase + r;
                if (g < 2) {
                    const bf16 th = f2b(tb);
                    Th[trow][col] = th;
                    Tl[trow][col] = f2b(tb - b2f(th));
                    xdp[r] += tb * tb;
                } else {
                    Vs[trow][col] = f2b(tb);
                }
            }
        }
        if (g < 2) {
            #pragma unroll
            for (int r = 0; r < 4; ++r) {
                float v = xdp[r];
                v += __shfl_xor(v, 1, 64); v += __shfl_xor(v, 2, 64);
                v += __shfl_xor(v, 4, 64); v += __shfl_xor(v, 8, 64);
                if (g == 0) xdK[r] = 0.5f * v; else xdQ[r] = 0.5f * v;
            }
        }
        __syncthreads();   // Th/Tl (or Vs) ready; Wh/Wl reads done
        if (g < 2) {
            f32x4 acc2[2] = {};
            #pragma unroll
            for (int k0 = 0; k0 < 64; k0 += 32) {
                const frag8 ath = *(const frag8*)(&Th[(wv << 4) + l15][k8 + k0]);
                const frag8 atl = *(const frag8*)(&Tl[(wv << 4) + l15][k8 + k0]);
                #pragma unroll
                for (int nt = 0; nt < 2; ++nt) {
                    const frag8 bw = *(const frag8*)(&wps[(nt << 4) + l15][k8 + k0]);
                    acc2[nt] = __builtin_amdgcn_mfma_f32_16x16x32_bf16(ath, bw, acc2[nt], 0, 0, 0);
                    acc2[nt] = __builtin_amdgcn_mfma_f32_16x16x32_bf16(atl, bw, acc2[nt], 0, 0, 0);
                }
            }
            #pragma unroll
            for (int nt = 0; nt < 2; ++nt)
                #pragma unroll
                for (int r = 0; r < 4; ++r) {
                    const float xd = (g == 0) ? xdK[r] : xdQ[r];
                    const float p = expf(fminf(acc2[nt][r] - xd, 30.f)) * INV_SQRT_M;
                    KPs[(wv << 4) + rbase + r][(nt << 4) + l15] = f2b(p);
                }
            __syncthreads();   // KPs ready
            bf16* dstP = (g == 0 ? KP : QP) + ((ll)blockIdx.x * 64 + srow) * 32 + scol;
            *(uint4*)dstP = *(const uint4*)(&KPs[srow][scol]);
            __syncthreads();   // KPs reads done before next group reuses it
        } else {
            bf16* dstV = V + ((ll)blockIdx.x * 64 + srow) * 64 + colg;
            *(uint4*)dstV       = *(const uint4*)(&Vs[srow][colg]);
            *(uint4*)(dstV + 8) = *(const uint4*)(&Vs[srow][colg + 8]);
        }
    }
}

// ---- MFMA reduce over tokens: red[n*32+m] += sum_t V[t][n]*KP[t][m]; ksum via ones ----
__global__ __launch_bounds__(256) void k_reduce(
    const bf16* __restrict__ kpB, const bf16* __restrict__ vB, const int vstride,
    const int T, float* __restrict__ redBase, const int chunk)
{
    __shared__ bf16 VT[64][72];   // [n][t]
    __shared__ bf16 KT[32][72];   // [m][t]
    const int bz = blockIdx.y;
    const bf16* kp = kpB + (ll)bz * T * 32;
    const bf16* v  = vB + (ll)bz * T * (ll)vstride;
    float* red = redBase + (ll)bz * 2080;
    const int tid = threadIdx.x;
    const int wv = tid >> 6, lane = tid & 63;
    const int l15 = lane & 15, k8 = (lane >> 4) << 3, rbase = (lane >> 4) << 2;
    const int t0 = blockIdx.x * chunk;

    frag8 ones;
    {
        union { bf16 h; short s; } u; u.h = f2b(1.f);
        #pragma unroll
        for (int i = 0; i < 8; ++i) ones[i] = u.s;
    }

    f32x4 acc[2] = {};
    f32x4 accK[2] = {};

    for (int tt = 0; tt < chunk; tt += 64) {
        const int tb = t0 + tt;
        __syncthreads();
        {
            const int tk = tid >> 2, n0 = (tid & 3) << 4;
            const bf16* src = v + (ll)(tb + tk) * vstride + n0;
            bf16 tmp[16];
            *(uint4*)tmp       = *(const uint4*)src;
            *(uint4*)(tmp + 8) = *(const uint4*)(src + 8);
            #pragma unroll
            for (int j = 0; j < 16; ++j) VT[n0 + j][tk] = tmp[j];
        }
        {
            const int tk = tid >> 2, m0 = (tid & 3) << 3;
            const bf16* src = kp + (ll)(tb + tk) * 32 + m0;
            bf16 tmp[8];
            *(uint4*)tmp = *(const uint4*)src;
            #pragma unroll
            for (int j = 0; j < 8; ++j) KT[m0 + j][tk] = tmp[j];
        }
        __syncthreads();
        #pragma unroll
        for (int ks = 0; ks < 2; ++ks) {
            const frag8 af = *(const frag8*)(&VT[(wv << 4) + l15][k8 + ks * 32]);
            #pragma unroll
            for (int tn = 0; tn < 2; ++tn) {
                const frag8 bfv = *(const frag8*)(&KT[(tn << 4) + l15][k8 + ks * 32]);
                acc[tn] = __builtin_amdgcn_mfma_f32_16x16x32_bf16(af, bfv, acc[tn], 0, 0, 0);
            }
            if (wv == 0) {
                #pragma unroll
                for (int tn = 0; tn < 2; ++tn) {
                    const frag8 bfv = *(const frag8*)(&KT[(tn << 4) + l15][k8 + ks * 32]);
                    accK[tn] = __builtin_amdgcn_mfma_f32_16x16x32_bf16(ones, bfv, accK[tn], 0, 0, 0);
                }
            }
        }
    }
    #pragma unroll
    for (int tn = 0; tn < 2; ++tn) {
        const int m = (tn << 4) + l15;
        #pragma unroll
        for (int r = 0; r < 4; ++r) {
            const int n = (wv << 4) + rbase + r;
            atomicAdd(&red[n * 32 + m], acc[tn][r]);
        }
    }
    if (wv == 0 && (lane >> 4) == 0) {
        #pragma unroll
        for (int tn = 0; tn < 2; ++tn)
            atomicAdd(&red[2048 + (tn << 4) + l15], accK[tn][0]);
    }
}

// ---- merged post-attention + LN + MLP (bit-identical to old k_posta -> k_mlpln) ----
__global__ __launch_bounds__(256) void k_postmlp(
    const bf16* __restrict__ qpB, const float* __restrict__ redBase,
    const bf16* __restrict__ vB, const int vstride,
    const bf16* __restrict__ pw, const bf16* __restrict__ pb,
    const bf16* __restrict__ n2g, const bf16* __restrict__ n2b,
    const bf16* __restrict__ w1, const bf16* __restrict__ b1,
    const bf16* __restrict__ w2, const bf16* __restrict__ b2,
    bf16* outB, const int T)
{
    __shared__ __align__(16) char smem[47232];
    bf16 (*QPs)[40] = (bf16(*)[40])(smem);
    bf16 (*KH)[40]  = (bf16(*)[40])(smem + 5120);
    bf16 (*KL)[40]  = (bf16(*)[40])(smem + 10240);
    float (*Cs)[72] = (float(*)[72])(smem);
    bf16 (*W1s)[72] = (bf16(*)[72])(smem);
    bf16 (*W2s)[72] = (bf16(*)[72])(smem + 9216);
    bf16 (*PWs)[72] = (bf16(*)[72])(smem + 18432);
    bf16 (*Gs)[72]  = (bf16(*)[72])(smem + 18432);
    bf16 (*Y0H)[72] = (bf16(*)[72])(smem + 27648);
    bf16 (*Ys)[72]  = (bf16(*)[72])(smem + 27648);
    bf16 (*Y0L)[72] = (bf16(*)[72])(smem + 36864);
    bf16 (*Hn)[72]  = (bf16(*)[72])(smem + 36864);
    float* invs  = (float*)(smem + 46080);
    float* pbs   = (float*)(smem + 46336);
    float* ksums = (float*)(smem + 46592);
    float* mns   = (float*)(smem + 46720);
    float* rss   = (float*)(smem + 46976);

    const int tid = threadIdx.x;
    const int bz = blockIdx.y;
    const float* red = redBase + (ll)bz * 2080;
    const bf16* qp = qpB + (ll)bz * (ll)T * 32;
    const bf16* v  = vB + (ll)bz * (ll)T * (ll)vstride;
    bf16* out = outB + (ll)bz * (ll)T * 64;
    const ll m0 = (ll)blockIdx.x * 64;

    const int lr = tid >> 2;
    const int lc8 = (tid & 3) << 3;
    const int lc16 = (tid & 3) << 4;

    *(uint4*)(&QPs[lr][lc8]) = *(const uint4*)(qp + (m0 + lr) * 32 + lc8);
    *(uint4*)(&PWs[lr][lc16])     = *(const uint4*)(pw + lr * 64 + lc16);
    *(uint4*)(&PWs[lr][lc16 + 8]) = *(const uint4*)(pw + lr * 64 + lc16 + 8);
    {
        const int i0 = tid * 8;
        const float4 a = *(const float4*)(red + i0);
        const float4 b = *(const float4*)(red + i0 + 4);
        const int n = i0 >> 5, m = i0 & 31;
        float xs[8] = {a.x, a.y, a.z, a.w, b.x, b.y, b.z, b.w};
        #pragma unroll
        for (int k = 0; k < 8; ++k) {
            const bf16 h = f2b(xs[k]);
            KH[n][m + k] = h;
            KL[n][m + k] = f2b(xs[k] - b2f(h));
        }
    }
    if (tid < 32) ksums[tid] = red[2048 + tid];
    if (tid < 64) pbs[tid] = b2f(pb[tid]);
    __syncthreads();

    if (tid < 64) {
        float D = D_EPS;
        #pragma unroll
        for (int m = 0; m < 32; ++m) D += b2f(QPs[tid][m]) * ksums[m];
        invs[tid] = 1.f / D;
    }

    const int wv = tid >> 6, lane = tid & 63;
    const int l15 = lane & 15;
    const int mr = (wv << 4) + l15;
    const int k8 = (lane >> 4) << 3;
    const int rbase = (lane >> 4) << 2;

    f32x4 acc[4] = {};
    {
        const frag8 af = *(const frag8*)(&QPs[mr][k8]);
        #pragma unroll
        for (int tn = 0; tn < 4; ++tn) {
            const int nr = (tn << 4) + l15;
            const frag8 bh = *(const frag8*)(&KH[nr][k8]);
            acc[tn] = __builtin_amdgcn_mfma_f32_16x16x32_bf16(af, bh, acc[tn], 0, 0, 0);
            const frag8 bl = *(const frag8*)(&KL[nr][k8]);
            acc[tn] = __builtin_amdgcn_mfma_f32_16x16x32_bf16(af, bl, acc[tn], 0, 0, 0);
        }
    }
    #pragma unroll
    for (int tn = 0; tn < 4; ++tn) {
        const int n = (tn << 4) + l15;
        #pragma unroll
        for (int r = 0; r < 4; ++r) {
            const float x = acc[tn][r];
            const bf16 h = f2b(x);
            Y0H[(wv << 4) + rbase + r][n] = h;
            Y0L[(wv << 4) + rbase + r][n] = f2b(x - b2f(h));
        }
    }
    __syncthreads();

    f32x4 acc2[4] = {};
    #pragma unroll
    for (int k0 = 0; k0 < 64; k0 += 32) {
        const frag8 ah = *(const frag8*)(&Y0H[mr][k8 + k0]);
        const frag8 al = *(const frag8*)(&Y0L[mr][k8 + k0]);
        #pragma unroll
        for (int tn = 0; tn < 4; ++tn) {
            const frag8 bw = *(const frag8*)(&PWs[(tn << 4) + l15][k8 + k0]);
            acc2[tn] = __builtin_amdgcn_mfma_f32_16x16x32_bf16(ah, bw, acc2[tn], 0, 0, 0);
            acc2[tn] = __builtin_amdgcn_mfma_f32_16x16x32_bf16(al, bw, acc2[tn], 0, 0, 0);
        }
    }
    #pragma unroll
    for (int tn = 0; tn < 4; ++tn) {
        const int n = (tn << 4) + l15;
        #pragma unroll
        for (int r = 0; r < 4; ++r) {
            const int row = (wv << 4) + rbase + r;
            Cs[row][n] = acc2[tn][r] * invs[row] + pbs[n];
        }
    }
    __syncthreads();

    {
        const int row = tid >> 2;
        const bf16* vsrc = v + (m0 + row) * (ll)vstride + lc16;
        #pragma unroll
        for (int hh = 0; hh < 2; ++hh) {
            float vv[8];
            up8(vsrc + hh * 8, vv);
            const float* cp = &Cs[row][lc16 + hh * 8];
            uint4 st;
            st.x = pk2f(cp[0] + vv[0], cp[1] + vv[1]);
            st.y = pk2f(cp[2] + vv[2], cp[3] + vv[3]);
            st.z = pk2f(cp[4] + vv[4], cp[5] + vv[5]);
            st.w = pk2f(cp[6] + vv[6], cp[7] + vv[7]);
            *(uint4*)(&Ys[row][lc16 + hh * 8]) = st;
        }
    }
    __syncthreads();

    if (tid < 64) {
        float s = 0.f, s2 = 0.f;
        #pragma unroll
        for (int n = 0; n < 64; ++n) { const float vv = b2f(Ys[tid][n]); s += vv; s2 += vv * vv; }
        const float mn = s * (1.f / 64.f);
        const float var = fmaxf(s2 * (1.f / 64.f) - mn * mn, 0.f);
        mns[tid] = mn; rss[tid] = rsqrtf(var + LN_EPS);
    }
    *(uint4*)(&W1s[lr][lc16])     = *(const uint4*)(w1 + lr * 64 + lc16);
    *(uint4*)(&W1s[lr][lc16 + 8]) = *(const uint4*)(w1 + lr * 64 + lc16 + 8);
    *(uint4*)(&W2s[lr][lc16])     = *(const uint4*)(w2 + lr * 64 + lc16);
    *(uint4*)(&W2s[lr][lc16 + 8]) = *(const uint4*)(w2 + lr * 64 + lc16 + 8);
    __syncthreads();

    for (int i = tid; i < 4096; i += 256) {
        const int r = i >> 6, c = i & 63;
        Hn[r][c] = f2b((b2f(Ys[r][c]) - mns[r]) * rss[r] * b2f(n2g[c]) + b2f(n2b[c]));
    }
    __syncthreads();

    f32x4 accm[4] = {};
    #pragma unroll
    for (int k0 = 0; k0 < 64; k0 += 32) {
        const frag8 af = *(const frag8*)(&Hn[mr][k8 + k0]);
        #pragma unroll
        for (int tn = 0; tn < 4; ++tn) {
            const frag8 bfv = *(const frag8*)(&W1s[(tn << 4) + l15][k8 + k0]);
            accm[tn] = __builtin_amdgcn_mfma_f32_16x16x32_bf16(af, bfv, accm[tn], 0, 0, 0);
        }
    }
    #pragma unroll
    for (int tn = 0; tn < 4; ++tn) {
        const int n = (tn << 4) + l15;
        const float bv = b2f(b1[n]);
        #pragma unroll
        for (int r = 0; r < 4; ++r) {
            float vg = accm[tn][r] + bv;
            vg = 0.5f * vg * (1.f + erff(vg * 0.70710678118654752f));
            Gs[(wv << 4) + rbase + r][n] = f2b(vg);
        }
    }
    __syncthreads();

    f32x4 accn[4] = {};
    #pragma unroll
    for (int k0 = 0; k0 < 64; k0 += 32) {
        const frag8 af = *(const frag8*)(&Gs[mr][k8 + k0]);
        #pragma unroll
        for (int tn = 0; tn < 4; ++tn) {
            const frag8 bfv = *(const frag8*)(&W2s[(tn << 4) + l15][k8 + k0]);
            accn[tn] = __builtin_amdgcn_mfma_f32_16x16x32_bf16(af, bfv, accn[tn], 0, 0, 0);
        }
    }
    #pragma unroll
    for (int tn = 0; tn < 4; ++tn) {
        const int n = (tn << 4) + l15;
        const float bv = b2f(b2[n]);
        #pragma unroll
        for (int r = 0; r < 4; ++r)
            Hn[(wv << 4) + rbase + r][n] = f2b(accn[tn][r] + bv);
    }
    __syncthreads();

    {
        const int row = tid >> 2;
        bf16* dst = out + (m0 + row) * 64 + lc16;
        #pragma unroll
        for (int hh = 0; hh < 2; ++hh) {
            float sv[8], rv[8];
            up8(&Hn[row][lc16 + hh * 8], sv);
            up8(&Ys[row][lc16 + hh * 8], rv);
            uint4 st;
            st.x = pk2f(sv[0] + rv[0], sv[1] + rv[1]);
            st.y = pk2f(sv[2] + rv[2], sv[3] + rv[3]);
            st.z = pk2f(sv[4] + rv[4], sv[5] + rv[5]);
            st.w = pk2f(sv[6] + rv[6], sv[7] + rv[7]);
            *(uint4*)(dst + hh * 8) = st;
        }
    }
}

// ---- unfold 3x3 s2 p1, token-major [Hin*Hin,64] -> [Ho*Ho,576] (+opt LN) ----
__global__ __launch_bounds__(256) void k_unfold576(
    const bf16* __restrict__ in, const int Hin, const int Ho,
    const bf16* __restrict__ g, const bf16* __restrict__ bb,
    const int do_ln, bf16* __restrict__ A,
    const ll inBStride, const ll outBStride)
{
    in += (ll)blockIdx.y * inBStride;
    A  += (ll)blockIdx.y * outBStride;
    const int t = blockIdx.x * 4 + (threadIdx.x >> 6);
    const int l = threadIdx.x & 63;
    const int ho = t / Ho, wo = t - ho * Ho;
    float vals[9];
    float s = 0.f;
    #pragma unroll
    for (int r = 0; r < 9; ++r) {
        const int d = l + (r << 6);
        const int c = d / 9;
        const int rr = d - c * 9;
        const int i = rr / 3, j = rr - i * 3;
        const int hh = 2 * ho + i - 1, ww = 2 * wo + j - 1;
        float val = 0.f;
        if (hh >= 0 && hh < Hin && ww >= 0 && ww < Hin)
            val = b2f(in[((ll)hh * Hin + ww) * 64 + c]);
        vals[r] = val; s += val;
    }
    bf16* out = A + (ll)t * 576;
    if (do_ln) {
        #pragma unroll
        for (int o = 32; o > 0; o >>= 1) s += __shfl_xor(s, o, 64);
        const float mean = s * (1.f / 576.f);
        float s2 = 0.f;
        #pragma unroll
        for (int r = 0; r < 9; ++r) { const float dd = vals[r] - mean; s2 += dd * dd; }
        #pragma unroll
        for (int o = 32; o > 0; o >>= 1) s2 += __shfl_xor(s2, o, 64);
        const float rs = rsqrtf(s2 * (1.f / 576.f) + LN_EPS);
        #pragma unroll
        for (int r = 0; r < 9; ++r) {
            const int d = l + (r << 6);
            out[d] = f2b((vals[r] - mean) * rs * b2f(g[d]) + b2f(bb[d]));
        }
    } else {
        #pragma unroll
        for (int r = 0; r < 9; ++r) out[l + (r << 6)] = f2b(vals[r]);
    }
}

// ---- MFMA bf16 GEMM BM=64: C[M,N] = A@W^T + bias (+res); double-buffered ----
// Exact R5 configuration (proven): dim3(gridM, gridN) grid, no swizzle.
__global__ __launch_bounds__(256) void k_gemm(
    const bf16* __restrict__ A, const int lda,
    const bf16* __restrict__ W,
    const bf16* __restrict__ bias,
    const bf16* res, const int ldres,
    void* C, const int ldc, const ll mOff,
    const int K, const int* outm)
{
    __shared__ bf16 As[2][64][40];
    __shared__ bf16 Bs[2][64][40];
    __shared__ bf16 Cs[64][72];
    const int tid = threadIdx.x;
    const int wv = tid >> 6;
    const int lane = tid & 63;
    const ll m0 = (ll)blockIdx.x * 64;
    const int n0 = blockIdx.y * 64;
    f32x4 acc[4] = {};
    const int lr = tid >> 2;
    const int lc = (tid & 3) << 3;
    const int mr = (wv << 4) + (lane & 15);
    const int k8 = (lane >> 4) << 3;
    const bf16* Ag = A + (m0 + lr) * (ll)lda + lc;
    const bf16* Wg = W + (ll)(n0 + lr) * K + lc;

    uint4 av  = *(const uint4*)(Ag);
    uint4 wv4 = *(const uint4*)(Wg);
    *(uint4*)(&As[0][lr][lc]) = av;
    *(uint4*)(&Bs[0][lr][lc]) = wv4;
    int cur = 0;
    __syncthreads();
    for (int k0 = 0; k0 < K; k0 += 32) {
        const bool nxt = (k0 + 32 < K);
        if (nxt) {
            av  = *(const uint4*)(Ag + k0 + 32);
            wv4 = *(const uint4*)(Wg + k0 + 32);
        }
        const frag8 af = *(const frag8*)(&As[cur][mr][k8]);
        #pragma unroll
        for (int tn = 0; tn < 4; ++tn) {
            const frag8 bfv = *(const frag8*)(&Bs[cur][(tn << 4) + (lane & 15)][k8]);
            acc[tn] = __builtin_amdgcn_mfma_f32_16x16x32_bf16(af, bfv, acc[tn], 0, 0, 0);
        }
        if (nxt) {
            *(uint4*)(&As[cur ^ 1][lr][lc]) = av;
            *(uint4*)(&Bs[cur ^ 1][lr][lc]) = wv4;
        }
        __syncthreads();
        cur ^= 1;
    }
    const int om = outm ? *outm : 0;
    const int rbase = (lane >> 4) << 2;
    if (om) {
        #pragma unroll
        for (int tn = 0; tn < 4; ++tn) {
            const int n = n0 + (tn << 4) + (lane & 15);
            const float bv = bias ? b2f(bias[n]) : 0.f;
            #pragma unroll
            for (int r = 0; r < 4; ++r) {
                const ll m = m0 + (wv << 4) + rbase + r;
                float v = acc[tn][r] + bv;
                if (res) v += b2f(res[m * (ll)ldres + n]);
                ((float*)C)[(m + mOff) * (ll)ldc + n] = v;
            }
        }
        return;
    }
    #pragma unroll
    for (int tn = 0; tn < 4; ++tn) {
        const int nl = (tn << 4) + (lane & 15);
        const float bv = bias ? b2f(bias[n0 + nl]) : 0.f;
        #pragma unroll
        for (int r = 0; r < 4; ++r) {
            const ll m = m0 + (wv << 4) + rbase + r;
            float v = acc[tn][r] + bv;
            if (res) v += b2f(res[m * (ll)ldres + n0 + nl]);
            Cs[(wv << 4) + rbase + r][nl] = f2b(v);
        }
    }
    __syncthreads();
    const int row = tid >> 2;
    const int colg = (tid & 3) << 4;
    bf16* dst = (bf16*)C + (m0 + mOff + row) * (ll)ldc + n0 + colg;
    *(uint4*)dst       = *(const uint4*)(&Cs[row][colg]);
    *(uint4*)(dst + 8) = *(const uint4*)(&Cs[row][colg + 8]);
}

// ---- MFMA bf16 GEMM BM=128 x BN=128 (final projection): 16 MFMAs/wave/K-step ----
// 1-D grid, bijective XCD-chunk swizzle. Per-output-element K-order identical
// to BM=64 version (bit-identical numerics).
__global__ __launch_bounds__(256) void k_gemm128(
    const bf16* __restrict__ A, const int lda,
    const bf16* __restrict__ W,
    const bf16* __restrict__ bias,
    void* C, const int ldc, const ll mOff,
    const int K, const int* outm, const int gridN)
{
    // LDS: As[2][128][40] 20480 + Bs[2][128][40] 20480 = 40960 -> ~4 blocks/CU.
    __shared__ __align__(16) char smem[40960];
    bf16 (*As)[128][40] = (bf16(*)[128][40])smem;
    bf16 (*Bs)[128][40] = (bf16(*)[128][40])(smem + 20480);
    bf16 (*Cs)[136]     = (bf16(*)[136])smem;       // [128][136] 34816, alias after loop

    const int nwg = gridDim.x;
    const int orig = blockIdx.x;
    const int xcd = orig & 7;
    const int q = nwg >> 3, r = nwg & 7;
    const int wgid = (xcd < r ? xcd * (q + 1) : r * (q + 1) + (xcd - r) * q)
                     + (orig >> 3);
    const int mTile = wgid / gridN;
    const int nTile = wgid - mTile * gridN;
    const ll m0 = (ll)mTile * 128;
    const int n0 = nTile * 128;

    const int tid = threadIdx.x;
    const int wv = tid >> 6, lane = tid & 63, l15 = lane & 15;
    const int k8 = (lane >> 4) << 3;
    const int rbase = (lane >> 4) << 2;
    const int mr0 = (wv << 5) + l15;          // wave owns m-rows [wv*32, wv*32+32)
    const int sr = tid >> 1, sc = (tid & 1) << 4;
    const bf16* Ag = A + (m0 + sr) * (ll)lda + sc;
    const bf16* Wg = W + (ll)(n0 + sr) * K + sc;

    f32x4 acc[2][8] = {};
    uint4 a0 = *(const uint4*)(Ag);
    uint4 a1 = *(const uint4*)(Ag + 8);
    uint4 b0 = *(const uint4*)(Wg);
    uint4 b1 = *(const uint4*)(Wg + 8);
    *(uint4*)(&(*As)[sr][sc])     = a0;
    *(uint4*)(&(*As)[sr][sc + 8]) = a1;
    *(uint4*)(&(*Bs)[sr][sc])     = b0;
    *(uint4*)(&(*Bs)[sr][sc + 8]) = b1;
    int cur = 0;
    __syncthreads();
    for (int k0 = 0; k0 < K; k0 += 32) {
        const bool nxt = (k0 + 32 < K);
        if (nxt) {
            a0 = *(const uint4*)(Ag + k0 + 32);
            a1 = *(const uint4*)(Ag + k0 + 40);
            b0 = *(const uint4*)(Wg + k0 + 32);
            b1 = *(const uint4*)(Wg + k0 + 40);
        }
        const frag8 af0 = *(const frag8*)(&As[cur][mr0][k8]);
        const frag8 af1 = *(const frag8*)(&As[cur][mr0 + 16][k8]);
        #pragma unroll
        for (int tn = 0; tn < 8; ++tn) {
            const frag8 bfv = *(const frag8*)(&Bs[cur][(tn << 4) + l15][k8]);
            acc[0][tn] = __builtin_amdgcn_mfma_f32_16x16x32_bf16(af0, bfv, acc[0][tn], 0, 0, 0);
            acc[1][tn] = __builtin_amdgcn_mfma_f32_16x16x32_bf16(af1, bfv, acc[1][tn], 0, 0, 0);
        }
        if (nxt) {
            *(uint4*)(&As[cur ^ 1][sr][sc])     = a0;
            *(uint4*)(&As[cur ^ 1][sr][sc + 8]) = a1;
            *(uint4*)(&Bs[cur ^ 1][sr][sc])     = b0;
            *(uint4*)(&Bs[cur ^ 1][sr][sc + 8]) = b1;
        }
        __syncthreads();
        cur ^= 1;
    }
    const int om = outm ? *outm : 0;
    if (om) {   // fp32 output: direct stores (R7-proven)
        #pragma unroll
        for (int mi = 0; mi < 2; ++mi)
            #pragma unroll
            for (int tn = 0; tn < 8; ++tn) {
                const int n = n0 + (tn << 4) + l15;
                const float bv = bias ? b2f(bias[n]) : 0.f;
                #pragma unroll
                for (int rr2 = 0; rr2 < 4; ++rr2) {
                    const ll m = m0 + (wv << 5) + (mi << 4) + rbase + rr2;
                    ((float*)C)[(m + mOff) * (ll)ldc + n] = acc[mi][tn][rr2] + bv;
                }
            }
        return;
    }
    // bf16 output: stage in LDS (aliases As/Bs, dead after final barrier)
    #pragma unroll
    for (int mi = 0; mi < 2; ++mi)
        #pragma unroll
        for (int tn = 0; tn < 8; ++tn) {
            const int nl = (tn << 4) + l15;
            const float bv = bias ? b2f(bias[n0 + nl]) : 0.f;
            #pragma unroll
            for (int rr2 = 0; rr2 < 4; ++rr2)
                Cs[(wv << 5) + (mi << 4) + rbase + rr2][nl] = f2b(acc[mi][tn][rr2] + bv);
        }
    __syncthreads();
    const int row = tid >> 1;
    const int colg = (tid & 1) << 6;
    bf16* dst = (bf16*)C + (m0 + mOff + row) * (ll)ldc + n0 + colg;
    #pragma unroll
    for (int u = 0; u < 8; ++u)
        *(uint4*)(dst + u * 8) = *(const uint4*)(&Cs[row][colg + u * 8]);
}

// ---- MFMA prm_exp for stage-2 (k and q passes) + RED zeroing ----
__global__ __launch_bounds__(256) void k_fusedP2(
    const bf16* __restrict__ kqv, const bf16* __restrict__ pw,
    bf16* __restrict__ KP, bf16* __restrict__ QP,
    float* __restrict__ redBase, const int T)
{
    __shared__ __align__(16) char smem[19200];
    bf16 (*Ks)[72]  = (bf16(*)[72])(smem);            // 9216
    bf16 (*wps)[72] = (bf16(*)[72])(smem + 9216);     // 4608
    bf16 (*KPs)[40] = (bf16(*)[40])(smem + 13824);    // 5120
    float* xds = (float*)(smem + 18944);              // 256

    const int tid = threadIdx.x;
    const int bz = blockIdx.y;
    {
        const int i = tid * 8;
        *(uint4*)(&wps[i >> 6][i & 63]) = *(const uint4*)(pw + i);
    }
    if (blockIdx.x == 0) {
        float* red = redBase + (ll)bz * 2080;
        for (int i = tid; i < 2080; i += 256) red[i] = 0.f;
    }
    const ll gt0 = (ll)bz * T + (ll)blockIdx.x * 64;
    const int srow = tid >> 2;
    const int colg = (tid & 3) << 4;
    const int scol = (tid & 3) << 3;
    const int wv = tid >> 6, lane = tid & 63;
    const int l15 = lane & 15, k8 = (lane >> 4) << 3, rbase = (lane >> 4) << 2;

    #pragma unroll
    for (int p = 0; p < 2; ++p) {          // 0 = k pass, 1 = q pass
        const bf16* src = kqv + (gt0 + srow) * 192 + p * 64 + colg;
        const uint4 u0 = *(const uint4*)src;
        const uint4 u1 = *(const uint4*)(src + 8);
        *(uint4*)(&Ks[srow][colg])     = u0;
        *(uint4*)(&Ks[srow][colg + 8]) = u1;
        float f0[8], f1[8];
        up8u(u0, f0); up8u(u1, f1);
        float s2 = 0.f;
        #pragma unroll
        for (int k = 0; k < 8; ++k) s2 += f0[k] * f0[k] + f1[k] * f1[k];
        s2 += __shfl_xor(s2, 1, 64); s2 += __shfl_xor(s2, 2, 64);
        if ((tid & 3) == 0) xds[srow] = 0.5f * s2;
        __syncthreads();
        f32x4 acc2[2] = {};
        #pragma unroll
        for (int k0 = 0; k0 < 64; k0 += 32) {
            const frag8 af = *(const frag8*)(&Ks[(wv << 4) + l15][k8 + k0]);
            #pragma unroll
            for (int nt = 0; nt < 2; ++nt) {
                const frag8 bw = *(const frag8*)(&wps[(nt << 4) + l15][k8 + k0]);
                acc2[nt] = __builtin_amdgcn_mfma_f32_16x16x32_bf16(af, bw, acc2[nt], 0, 0, 0);
            }
        }
        #pragma unroll
        for (int nt = 0; nt < 2; ++nt)
            #pragma unroll
            for (int r = 0; r < 4; ++r) {
                const int trow = (wv << 4) + rbase + r;
                const float pv = expf(fminf(acc2[nt][r] - xds[trow], 30.f)) * INV_SQRT_M;
                KPs[trow][(nt << 4) + l15] = f2b(pv);
            }
        __syncthreads();
        bf16* dst = (p == 0 ? KP : QP) + (gt0 + srow) * 32 + scol;
        *(uint4*)dst = *(const uint4*)(&KPs[srow][scol]);
        __syncthreads();   // before next pass overwrites Ks/xds/KPs
    }
}

extern "C" void kernel_launch(void* const* d_in, const int* in_sizes, int n_in,
                              void* d_out, int out_size, void* d_ws, size_t ws_size,
                              hipStream_t stream)
{
    (void)in_sizes; (void)n_in; (void)out_size;
    const int T1 = 50176, T2 = 12544;
    char* ws = (char*)d_ws;

    // ---- cursor-based workspace allocation ----
    size_t cur = 0;
    auto alloc = [&](size_t bytes) {
        size_t r = cur; cur += (bytes + 127) & ~(size_t)127; return r;
    };
    static const int segIdx[28] = {0, 2, 3, 4, 5, 6, 7, 8, 9, 10, 11, 12, 13,
                                   14, 15, 16, 17, 18, 19, 20, 21, 22, 23, 24, 25, 26, 27, 28};
    static const int segN[28] = {1204224, 192, 4096, 64, 27, 27, 64, 64, 4096, 64, 4096, 64, 2048,
                                 110592, 192, 4096, 64, 576, 576, 64, 64, 4096, 64, 4096, 64, 2048,
                                 442368, 768};
    size_t segOff[28];
    for (int i = 0; i < 28; ++i) segOff[i] = alloc((size_t)segN[i] * 2);
    const size_t oMODE = alloc(256);
    const size_t oRED  = alloc(66560);             // 8 x 2080 fp32
    const size_t oW1P  = alloc(24576);             // hi/lo padded [192][32] bf16
    const size_t oBIG  = alloc(6422528);           // [T1,64]
    const size_t oKP   = alloc(3211264);           // [T1,32]
    const size_t oQP   = alloc(3211264);           // [T1,32]
    (void)oQP;

    bf16* P[28];
    for (int i = 0; i < 28; ++i) P[i] = (bf16*)(ws + segOff[i]);
    bf16* XC = P[0];
    bf16 *P1KQVB = P[1], *P1PW = P[2], *P1PB = P[3], *P1N1G = P[4], *P1N1B = P[5];
    bf16 *P1N2G = P[6], *P1N2B = P[7], *P1M1W = P[8], *P1M1B = P[9], *P1M2W = P[10];
    bf16 *P1M2B = P[11], *P1W = P[12];
    bf16 *P2KQVW = P[13], *P2KQVB = P[14], *P2PW = P[15], *P2PB = P[16];
    bf16 *P2N1G = P[17], *P2N1B = P[18], *P2N2G = P[19], *P2N2B = P[20];
    bf16 *P2M1W = P[21], *P2M1B = P[22], *P2M2W = P[23], *P2M2B = P[24], *P2W = P[25];
    bf16 *PROJW = P[26], *PROJB = P[27];

    int*   MODE = (int*)(ws + oMODE);
    float* REDF = (float*)(ws + oRED);
    bf16*  W1PH = (bf16*)(ws + oW1P);
    bf16*  W1PL = (bf16*)(ws + oW1P + 12288);
    bf16*  BIG  = (bf16*)(ws + oBIG);              // stage-1 V/Y/OUT (in-place chain)
    bf16*  KP   = (bf16*)(ws + oKP);
    bf16*  QP   = (bf16*)(ws + oKP + 3211264);
    bf16*  A2   = (bf16*)(ws + oKP);               // [T2,576] over dead KP/QP
    bf16*  KQV2F = (bf16*)d_out;                   // [8*T2,192] scratch in d_out
    bf16*  KP2F  = (bf16*)(ws + oKP);              // [8*T2,32]
    bf16*  QP2F  = (bf16*)(ws + oKP + 6422528);    // [8*T2,32]
    bf16*  YB2F  = (bf16*)(ws + oBIG);             // [8*T2,64] (over BIG, dead)
    bf16*  A3c   = (bf16*)(ws + oBIG + 12845056);  // [6272,576] chunk

    // ---- prologue ----
    k_sniff<<<1, 256, 0, stream>>>(d_in[0], MODE);
    CvTab tab;
    int cum = 0;
    for (int i = 0; i < 28; ++i) {
        tab.src[i] = d_in[segIdx[i]];
        tab.dstOff[i] = (int)(segOff[i] / 2);
        tab.cum[i] = cum;
        cum += segN[i];
    }
    tab.cum[28] = cum;
    k_convert_all<<<(cum + 255) / 256, 256, 0, stream>>>(tab, (bf16*)ws, MODE);
    k_prep<<<24, 256, 0, stream>>>(d_in[1], MODE, W1PH, W1PL);

    // ---- per-batch: stage 1 + stage-2 front ----
    for (int b = 0; b < 8; ++b) {
        float* REDb = REDF + (ll)b * 2080;
        k_fused1<<<784, 256, 0, stream>>>(XC, W1PH, W1PL, P1KQVB, P1N1G, P1N1B,
                                          P1W, KP, QP, BIG, REDb, b);
        k_reduce<<<dim3(392, 1), 256, 0, stream>>>(KP, BIG, 64, T1, REDb, 128);
        k_postmlp<<<dim3(784, 1), 256, 0, stream>>>(QP, REDb, BIG, 64, P1PW, P1PB,
            P1N2G, P1N2B, P1M1W, P1M1B, P1M2W, P1M2B, BIG, T1);
        k_unfold576<<<dim3(3136, 1), 256, 0, stream>>>(BIG, 224, 112, P2N1G, P2N1B,
                                                       1, A2, 0, 0);
        k_gemm<<<dim3(196, 3), 256, 0, stream>>>(A2, 576, P2KQVW, P2KQVB,
            nullptr, 0, KQV2F, 192, (ll)b * T2, 576, nullptr);
    }

    // ---- batched stage-2 tail (all 8 batches) ----
    k_fusedP2<<<dim3(196, 8), 256, 0, stream>>>(KQV2F, P2W, KP2F, QP2F, REDF, T2);
    k_reduce<<<dim3(98, 8), 256, 0, stream>>>(KP2F, KQV2F + 128, 192, T2, REDF, 128);
    k_postmlp<<<dim3(196, 8), 256, 0, stream>>>(QP2F, REDF, KQV2F + 128, 192,
        P2PW, P2PB, P2N2G, P2N2B, P2M1W, P2M1B, P2M2W, P2M2B, YB2F, T2);

    // ---- epilogue: stage-3 unfold + final projection ----
    const size_t needFull = oBIG + 12845056 + (size_t)25088 * 576 * 2;
    if (ws_size >= needFull) {
        bf16* A3 = (bf16*)(ws + oBIG + 12845056);  // [25088,576]
        k_unfold576<<<dim3(784, 8), 256, 0, stream>>>(
            YB2F, 112, 56, nullptr, nullptr, 0, A3, (ll)T2 * 64, (ll)3136 * 576);
        k_gemm128<<<1176, 256, 0, stream>>>(A3, 576, PROJW, PROJB,
            d_out, 768, 0, 576, MODE, 6);
    } else {
        for (int c = 0; c < 4; ++c) {
            k_unfold576<<<dim3(784, 2), 256, 0, stream>>>(
                YB2F + (ll)(2 * c) * T2 * 64, 112, 56, nullptr, nullptr, 0,
                A3c, (ll)T2 * 64, (ll)3136 * 576);
            k_gemm128<<<294, 256, 0, stream>>>(A3c, 576, PROJW, PROJB,
                d_out, 768, (ll)c * 6272, 576, MODE, 6);
        }
    }
}